// Round 2
// baseline (11274.661 us; speedup 1.0000x reference)
//
#include <hip/hip_runtime.h>
#include <stdint.h>

// BiLSTM (3-layer, bidirectional, 3-gate custom cell, highway) for MI355X.
//
// R10: hard-pin W_h in explicit AGPRs (a0..a143) + LDS for the remainder.
// Post-mortem R9: VGPR_Count still 128, scan still 3.52 ms. Volatile-asm
// loads forbid re-execution but NOT spilling: the allocator kept its 128-reg
// budget (waves_per_eu(2,2) ignored twice) and spilled the 192 pinned regs
// to scratch -> same ~350 KB/CU/step stream as R7's remat. Fix: bypass the
// allocator entirely. kk=0..5 weight fragments (36 x 16B) are written into
// NAMED AGPRs via v_accvgpr_write asm with per-register clobbers; the
// recurrent MFMAs are inline asm reading B straight from a[N:M] (ISA: B may
// be AGPR). kk=6,7 slices live in LDS (pitch 40 u16 = 80B, 16B-aligned,
// near-conflict-free), read via asm ds_read_b128 with counted lgkmcnt so
// the scheduler can't inflate arch pressure. Arch ~100 + 144 AGPR = ~244
// <= 256 -> 2 waves/SIMD, launchable. No builtin MFMA in k_scan -> the
// compiler never allocates AGPRs -> no clobber conflicts. s_nop fences
// cover VALU->MFMA-SrcC and MFMA->VALU-read hazards around the asm.
// Dataflow identical to the R5..R9 PASS (absmax 4.7e-3). Outputs fp32.

typedef unsigned short u16;
typedef unsigned int u32;
typedef unsigned long long u64;
typedef __attribute__((ext_vector_type(8))) short short8;   // 8 bf16
typedef __attribute__((ext_vector_type(4))) float f32x4;
typedef __attribute__((ext_vector_type(4))) u32 u32x4;

#define MFMA16(a, b, c) __builtin_amdgcn_mfma_f32_16x16x32_bf16((a), (b), (c), 0, 0, 0)

__device__ __forceinline__ float b2f(u16 u) {
  u32 v = ((u32)u) << 16;
  return __builtin_bit_cast(float, v);
}
__device__ __forceinline__ u16 f2b(float f) {  // round-to-nearest-even
  u32 u = __builtin_bit_cast(u32, f);
  u32 r = u + 0x7FFFu + ((u >> 16) & 1u);
  return (u16)(r >> 16);
}
__device__ __forceinline__ u16 f2h(float f) {  // fp32 -> fp16 bits
  return __builtin_bit_cast(u16, (_Float16)f);
}
__device__ __forceinline__ float h2f(u16 u) {  // fp16 bits -> fp32
  return (float)__builtin_bit_cast(_Float16, u);
}
// Overflow-proof activations: exp args always <= 0 -> no inf/NaN possible.
__device__ __forceinline__ float sigm(float x) {
  const float q = __expf(-fabsf(x));
  const float r = 1.f / (1.f + q);
  return x >= 0.f ? r : 1.f - r;
}
__device__ __forceinline__ float tanh_f(float x) {
  const float q = __expf(-2.f * fabsf(x));
  const float t = (1.f - q) / (1.f + q);
  return x >= 0.f ? t : -t;
}

// ---------------------------------------------------------------------------
// Convert x (fp32) -> bf16, vectorized float4.
// ---------------------------------------------------------------------------
__global__ void k_convert(const float* __restrict__ src, u16* __restrict__ dst, int n4) {
  int i = blockIdx.x * 256 + threadIdx.x;
  if (i < n4) {
    float4 v = ((const float4*)src)[i];
    ushort4 o;
    o.x = f2b(v.x); o.y = f2b(v.y); o.z = f2b(v.z); o.w = f2b(v.w);
    ((ushort4*)dst)[i] = o;
  }
}

// ---------------------------------------------------------------------------
// Transpose + convert all weight matrices (fp32 W[R][C] -> bf16 Wt[C][R]).
// ---------------------------------------------------------------------------
__global__ void k_transpose(const float* __restrict__ w0, const float* __restrict__ w1,
                            const float* __restrict__ w2, const float* __restrict__ w3,
                            const float* __restrict__ w4, const float* __restrict__ w5,
                            const float* __restrict__ w6, u16* __restrict__ wt) {
  int z = blockIdx.y;
  const float* src;
  int R, C;
  size_t off;
  switch (z) {
    case 0: src = w0; R = 512; C = 768; off = 0u; break;
    case 1: src = w1; R = 512; C = 768; off = 393216u; break;
    case 2: src = w2; R = 768; C = 768; off = 786432u; break;
    case 3: src = w3; R = 768; C = 768; off = 1376256u; break;
    case 4: src = w4; R = 768; C = 768; off = 1966080u; break;
    case 5: src = w5; R = 768; C = 768; off = 2555904u; break;
    default: src = w6; R = 512; C = 512; off = 3145728u; break;
  }
  size_t total = (size_t)R * C;
  size_t e = (size_t)blockIdx.x * 256 + threadIdx.x;
  if (e < total) {
    int cc = (int)(e / (size_t)R);
    int rr = (int)(e - (size_t)cc * R);
    wt[off + e] = f2b(src[(size_t)rr * C + cc]);
  }
}

// ---------------------------------------------------------------------------
// Pre-GEMM: Z[m][n] = fp16( sum_k A[m][k]*Wt[n][k] + bias[n] )  (row-major)
// A bf16 [32768][Ka]; grid=(256, 6, 2[dir]); block=256; 128x128 tile.
// EXACT R5 code (passing).
// ---------------------------------------------------------------------------
__launch_bounds__(256) __global__
void k_pregemm(const u16* __restrict__ A, int Ka,
               const u16* __restrict__ WtF, const u16* __restrict__ WtB, int Kb,
               const float* __restrict__ biasF, const float* __restrict__ biasB,
               u16* __restrict__ ZF, u16* __restrict__ ZB) {
  const int dir = blockIdx.z;
  const u16* Bt = dir ? WtB : WtF;
  const float* bias = dir ? biasB : biasF;
  u16* Z = dir ? ZB : ZF;
  const int m0 = blockIdx.x * 128;
  const int n0 = blockIdx.y * 128;

  __shared__ u16 lA[128 * 40];
  __shared__ u16 lB[128 * 40];

  const int tid = threadIdx.x;
  const int wave = tid >> 6, lane = tid & 63, quad = lane >> 4, l15 = lane & 15;
  const int wy = wave >> 1, wx = wave & 1;
  const int r = tid >> 2, kc = tid & 3;

  f32x4 acc[4][4];
#pragma unroll
  for (int i = 0; i < 4; ++i)
#pragma unroll
    for (int j = 0; j < 4; ++j)
#pragma unroll
      for (int k = 0; k < 4; ++k) acc[i][j][k] = 0.f;

  const int nk = Ka >> 5;
  for (int kk = 0; kk < nk; ++kk) {
    const u16* Ap = A + (size_t)(m0 + r) * Ka + kk * 32 + kc * 8;
    uint4 a0 = *(const uint4*)Ap;
    uint4 a1 = *(const uint4*)(Ap + (size_t)64 * Ka);
    const u16* Bp = Bt + (size_t)(n0 + r) * Kb + kk * 32 + kc * 8;
    uint4 b0 = *(const uint4*)Bp;
    uint4 b1 = *(const uint4*)(Bp + (size_t)64 * Kb);
    __syncthreads();
    *(uint4*)&lA[r * 40 + kc * 8] = a0;
    *(uint4*)&lA[(r + 64) * 40 + kc * 8] = a1;
    *(uint4*)&lB[r * 40 + kc * 8] = b0;
    *(uint4*)&lB[(r + 64) * 40 + kc * 8] = b1;
    __syncthreads();
    short8 af[4], bf[4];
#pragma unroll
    for (int mt = 0; mt < 4; ++mt)
      af[mt] = *(const short8*)&lA[(wy * 64 + mt * 16 + l15) * 40 + quad * 8];
#pragma unroll
    for (int nt = 0; nt < 4; ++nt)
      bf[nt] = *(const short8*)&lB[(wx * 64 + nt * 16 + l15) * 40 + quad * 8];
#pragma unroll
    for (int mt = 0; mt < 4; ++mt)
#pragma unroll
      for (int nt = 0; nt < 4; ++nt) acc[mt][nt] = MFMA16(af[mt], bf[nt], acc[mt][nt]);
  }

#pragma unroll
  for (int nt = 0; nt < 4; ++nt) {
    const int col = n0 + wx * 64 + nt * 16 + l15;
    const float bv = bias[col];
#pragma unroll
    for (int mt = 0; mt < 4; ++mt) {
      const int mbase = m0 + wy * 64 + mt * 16 + quad * 4;
#pragma unroll
      for (int rr = 0; rr < 4; ++rr)
        Z[(size_t)(mbase + rr) * 768 + col] = f2h(acc[mt][nt][rr] + bv);
    }
  }
}

// ---------------------------------------------------------------------------
// Highway: g = sigmoid(ys @ Wt_hw^T + b_hw); v = g*ys + (1-g)*cur.
// Dual outputs: Outb (bf16, may be null) / OutF (fp32 final, may be null).
// Cur/Outb may alias (owner-thread read-before-write); Ys never aliases.
// EXACT R5 code (passing).
// ---------------------------------------------------------------------------
__launch_bounds__(256) __global__
void k_highway(const u16* __restrict__ Ys, const u16* Cur,
               const u16* __restrict__ Wt, const float* __restrict__ bias,
               u16* Outb, float* OutF) {
  const int m0 = blockIdx.x * 128;
  const int n0 = blockIdx.y * 128;

  __shared__ u16 lA[128 * 40];
  __shared__ u16 lB[128 * 40];

  const int tid = threadIdx.x;
  const int wave = tid >> 6, lane = tid & 63, quad = lane >> 4, l15 = lane & 15;
  const int wy = wave >> 1, wx = wave & 1;
  const int r = tid >> 2, kc = tid & 3;

  f32x4 acc[4][4];
#pragma unroll
  for (int i = 0; i < 4; ++i)
#pragma unroll
    for (int j = 0; j < 4; ++j)
#pragma unroll
      for (int k = 0; k < 4; ++k) acc[i][j][k] = 0.f;

  for (int kk = 0; kk < 16; ++kk) {
    const u16* Ap = Ys + (size_t)(m0 + r) * 512 + kk * 32 + kc * 8;
    uint4 a0 = *(const uint4*)Ap;
    uint4 a1 = *(const uint4*)(Ap + (size_t)64 * 512);
    const u16* Bp = Wt + (size_t)(n0 + r) * 512 + kk * 32 + kc * 8;
    uint4 b0 = *(const uint4*)Bp;
    uint4 b1 = *(const uint4*)(Bp + (size_t)64 * 512);
    __syncthreads();
    *(uint4*)&lA[r * 40 + kc * 8] = a0;
    *(uint4*)&lA[(r + 64) * 40 + kc * 8] = a1;
    *(uint4*)&lB[r * 40 + kc * 8] = b0;
    *(uint4*)&lB[(r + 64) * 40 + kc * 8] = b1;
    __syncthreads();
    short8 af[4], bf[4];
#pragma unroll
    for (int mt = 0; mt < 4; ++mt)
      af[mt] = *(const short8*)&lA[(wy * 64 + mt * 16 + l15) * 40 + quad * 8];
#pragma unroll
    for (int nt = 0; nt < 4; ++nt)
      bf[nt] = *(const short8*)&lB[(wx * 64 + nt * 16 + l15) * 40 + quad * 8];
#pragma unroll
    for (int mt = 0; mt < 4; ++mt)
#pragma unroll
      for (int nt = 0; nt < 4; ++nt) acc[mt][nt] = MFMA16(af[mt], bf[nt], acc[mt][nt]);
  }

#pragma unroll
  for (int nt = 0; nt < 4; ++nt) {
    const int col = n0 + wx * 64 + nt * 16 + l15;
    const float bv = bias[col];
#pragma unroll
    for (int mt = 0; mt < 4; ++mt) {
      const int mbase = m0 + wy * 64 + mt * 16 + quad * 4;
#pragma unroll
      for (int rr = 0; rr < 4; ++rr) {
        const size_t idx = (size_t)(mbase + rr) * 512 + col;
        const float g = sigm(acc[mt][nt][rr] + bv);
        const float v = g * b2f(Ys[idx]) + (1.f - g) * b2f(Cur[idx]);
        if (Outb) Outb[idx] = f2b(v);
        if (OutF) OutF[idx] = v;
      }
    }
  }
}

// ---------------------------------------------------------------------------
// Scan: 4 blocks (dir = bx>>1, batch-half bh = bx&1), block=512 (8 waves).
// W_h residency plan (per wave, per step, zero L2 weight traffic):
//   kk=0..5  -> explicit AGPRs a0..a143 (hard-pinned, clobber-declared)
//   kk=6..7  -> LDS w_lds[2][768*40] (pitch 40 u16 = 80B, 16B aligned)
// MFMAs are inline asm (B from a[N:M] or "v"), afrag/weight LDS reads are
// asm ds_read_b128 with counted lgkmcnt waits (depth-1 prefetch).
// s_nop fences: VALU->MFMA SrcC (pre) and MFMA->VALU read (post).
// No builtin MFMA here -> compiler never touches AGPRs.
// ---------------------------------------------------------------------------

// pin one 16B weight fragment into AGPRs A0..A3
#define LP(A0, A1, A2, A3, G, NT, KK)                                              \
  do {                                                                             \
    short8 _w = *(const short8*)(Wt +                                              \
        (size_t)((G)*256 + wid * 32 + (NT)*16 + l15) * wt_pitch + koff +           \
        (KK)*32 + quad * 8);                                                       \
    u32x4 _u = __builtin_bit_cast(u32x4, _w);                                      \
    asm volatile("v_accvgpr_write_b32 a" #A0 ", %0\n\t"                            \
                 "v_accvgpr_write_b32 a" #A1 ", %1\n\t"                            \
                 "v_accvgpr_write_b32 a" #A2 ", %2\n\t"                            \
                 "v_accvgpr_write_b32 a" #A3 ", %3"                                \
                 :: "v"(_u[0]), "v"(_u[1]), "v"(_u[2]), "v"(_u[3])                 \
                 : "a" #A0, "a" #A1, "a" #A2, "a" #A3);                            \
  } while (0)

// D += A * B, B hard-coded AGPR range
#define MFA(LO, HI, ACC, AF)                                                       \
  asm volatile("v_mfma_f32_16x16x32_bf16 %0, %1, a[" #LO ":" #HI "], %0"           \
               : "+v"(ACC) : "v"(AF))

// D += A * B, B from VGPR (LDS-resident slices)
#define MFV(ACC, AF, BW)                                                           \
  asm volatile("v_mfma_f32_16x16x32_bf16 %0, %1, %2, %0"                           \
               : "+v"(ACC) : "v"(AF), "v"(BW))

#define DSR(DST, ADDR, OFF)                                                        \
  asm volatile("ds_read_b128 %0, %1 offset:" #OFF : "=v"(DST) : "v"(ADDR))

#define WLG(N) asm volatile("s_waitcnt lgkmcnt(" #N ")")

__global__ __attribute__((amdgpu_flat_work_group_size(512, 512), amdgpu_waves_per_eu(2, 2)))
void k_scan(const u16* __restrict__ ZF, const u16* __restrict__ ZB,
            const u16* __restrict__ WtF, const u16* __restrict__ WtB,
            int wt_pitch, int koff,
            const float* __restrict__ h0, const float* __restrict__ c0,
            u16* __restrict__ ys,            // bf16 [32768][512]; fwd 0-255, bwd 256-511
            float* __restrict__ hn, float* __restrict__ cn) {  // fp32, + dir*8192
  const int tid = threadIdx.x;
  const int wid = tid >> 6, lane = tid & 63, quad = lane >> 4, l15 = lane & 15;
  const int dir = blockIdx.x >> 1, bh = blockIdx.x & 1;
  const u16* Z = dir ? ZB : ZF;
  const u16* Wt = dir ? WtB : WtF;

  __shared__ u16 h_lds[2][16 * 264];   // double-buffered h(t) [b][k], pitch 264
  __shared__ u16 w_lds[2 * 768 * 40];  // W_h kk=6,7 slices, pitch 40 (80B rows)

  // ---- pin kk=0..5 weight fragments into a0..a143 (col n = g*256+wid*32+nt*16+l15)
  LP(0,1,2,3, 0,0,0);     LP(4,5,6,7, 0,0,1);     LP(8,9,10,11, 0,0,2);
  LP(12,13,14,15, 0,0,3); LP(16,17,18,19, 0,0,4); LP(20,21,22,23, 0,0,5);
  LP(24,25,26,27, 0,1,0); LP(28,29,30,31, 0,1,1); LP(32,33,34,35, 0,1,2);
  LP(36,37,38,39, 0,1,3); LP(40,41,42,43, 0,1,4); LP(44,45,46,47, 0,1,5);
  LP(48,49,50,51, 1,0,0); LP(52,53,54,55, 1,0,1); LP(56,57,58,59, 1,0,2);
  LP(60,61,62,63, 1,0,3); LP(64,65,66,67, 1,0,4); LP(68,69,70,71, 1,0,5);
  LP(72,73,74,75, 1,1,0); LP(76,77,78,79, 1,1,1); LP(80,81,82,83, 1,1,2);
  LP(84,85,86,87, 1,1,3); LP(88,89,90,91, 1,1,4); LP(92,93,94,95, 1,1,5);
  LP(96,97,98,99, 2,0,0);    LP(100,101,102,103, 2,0,1); LP(104,105,106,107, 2,0,2);
  LP(108,109,110,111, 2,0,3); LP(112,113,114,115, 2,0,4); LP(116,117,118,119, 2,0,5);
  LP(120,121,122,123, 2,1,0); LP(124,125,126,127, 2,1,1); LP(128,129,130,131, 2,1,2);
  LP(132,133,134,135, 2,1,3); LP(136,137,138,139, 2,1,4); LP(140,141,142,143, 2,1,5);

  // ---- fill w_lds with kk=6,7 slices: dst [slice][col*40 + q*8], 16B chunks
  for (int i = tid; i < 6144; i += 512) {
    const int slice = (i >= 3072) ? 1 : 0;
    const int rem = i - slice * 3072;
    const int col = rem >> 2, q = rem & 3;
    *(uint4*)&w_lds[slice * 30720 + col * 40 + q * 8] =
        *(const uint4*)(Wt + (size_t)col * wt_pitch + koff + 192 + slice * 32 + q * 8);
  }

  // ---- init h_lds[0] (broadcast h0; zero pad) and c regs
  for (int i = tid; i < 16 * 264; i += 512) {
    int k = i % 264;
    h_lds[0][i] = (k < 256) ? f2b(h0[k]) : (u16)0;
  }
  float cst[2][4];
#pragma unroll
  for (int nt = 0; nt < 2; ++nt) {
    const float cv = c0[wid * 32 + nt * 16 + l15];
#pragma unroll
    for (int rr = 0; rr < 4; ++rr) cst[nt][rr] = cv;
  }
  __syncthreads();

  // ---- LDS byte-address bases (low 32 bits of LDS generic addr = offset)
  const u32 hbase = (u32)(uintptr_t)&h_lds[0][0] + (u32)((l15 * 264 + quad * 8) * 2);
  const u32 wa6 = (u32)(uintptr_t)&w_lds[0] + (u32)(((wid * 32 + l15) * 40 + quad * 8) * 2);
  const u32 wa7 = wa6 + 61440u;  // + 768*40*2

  // ---- running per-lane pointers
  const size_t zlane = ((size_t)bh * 16 + quad * 4) * 768 + wid * 32 + l15;
  const u16* zp = Z + zlane + (dir ? (size_t)1023 * 24576 : (size_t)0);
  const ptrdiff_t zstep = dir ? -(ptrdiff_t)24576 : (ptrdiff_t)24576;
  const size_t yslane =
      ((size_t)bh * 16 + quad * 4) * 512 + (size_t)dir * 256 + wid * 32 + l15;
  u16* ysp = ys + yslane + (dir ? (size_t)1023 * 16384 : (size_t)0);
  const ptrdiff_t ystep = dir ? -(ptrdiff_t)16384 : (ptrdiff_t)16384;

  int par = 0;
#pragma unroll 1
  for (int t = 0; t < 1024; ++t) {
    // acc init from fp16 Z (bias included)
    f32x4 aI[2], aJ[2], aO[2];
#pragma unroll
    for (int nt = 0; nt < 2; ++nt)
#pragma unroll
      for (int rr = 0; rr < 4; ++rr) {
        aI[nt][rr] = h2f(zp[(size_t)rr * 768 + nt * 16]);
        aJ[nt][rr] = h2f(zp[(size_t)rr * 768 + 256 + nt * 16]);
        aO[nt][rr] = h2f(zp[(size_t)rr * 768 + 512 + nt * 16]);
      }

    const u32 ha = hbase + (par ? 8448u : 0u);
    short8 af0, af1;
    DSR(af0, ha, 0);
    DSR(af1, ha, 64);
    // fence: VALU(cvt) writes acc -> MFMA reads SrcC
    asm volatile("s_nop 3"
                 : "+v"(aI[0]), "+v"(aI[1]), "+v"(aJ[0]), "+v"(aJ[1]),
                   "+v"(aO[0]), "+v"(aO[1]));

    // kk0 (af0)
    WLG(1);
    MFA(0,3, aI[0], af0);   MFA(24,27, aI[1], af0);  MFA(48,51, aJ[0], af0);
    MFA(72,75, aJ[1], af0); MFA(96,99, aO[0], af0);  MFA(120,123, aO[1], af0);
    DSR(af0, ha, 128);
    // kk1 (af1)
    WLG(1);
    MFA(4,7, aI[0], af1);   MFA(28,31, aI[1], af1);  MFA(52,55, aJ[0], af1);
    MFA(76,79, aJ[1], af1); MFA(100,103, aO[0], af1); MFA(124,127, aO[1], af1);
    DSR(af1, ha, 192);
    // kk2 (af0)
    WLG(1);
    MFA(8,11, aI[0], af0);  MFA(32,35, aI[1], af0);  MFA(56,59, aJ[0], af0);
    MFA(80,83, aJ[1], af0); MFA(104,107, aO[0], af0); MFA(128,131, aO[1], af0);
    DSR(af0, ha, 256);
    // kk3 (af1)
    WLG(1);
    MFA(12,15, aI[0], af1); MFA(36,39, aI[1], af1);  MFA(60,63, aJ[0], af1);
    MFA(84,87, aJ[1], af1); MFA(108,111, aO[0], af1); MFA(132,135, aO[1], af1);
    DSR(af1, ha, 320);
    // kk4 (af0)
    WLG(1);
    MFA(16,19, aI[0], af0); MFA(40,43, aI[1], af0);  MFA(64,67, aJ[0], af0);
    MFA(88,91, aJ[1], af0); MFA(112,115, aO[0], af0); MFA(136,139, aO[1], af0);
    DSR(af0, ha, 384);
    // kk5 (af1)
    WLG(1);
    MFA(20,23, aI[0], af1); MFA(44,47, aI[1], af1);  MFA(68,71, aJ[0], af1);
    MFA(92,95, aJ[1], af1); MFA(116,119, aO[0], af1); MFA(140,143, aO[1], af1);
    // issue kk6 weight reads + kk7 afrag
    short8 w0_, w1_, w2_, w3_, w4_, w5_;
    DSR(w0_, wa6, 0);     DSR(w1_, wa6, 1280);  DSR(w2_, wa6, 20480);
    DSR(w3_, wa6, 21760); DSR(w4_, wa6, 40960); DSR(w5_, wa6, 42240);
    DSR(af1, ha, 448);
    // kk6 (af0 from offset 384, weights from LDS slice 0)
    WLG(1);
    MFV(aI[0], af0, w0_); MFV(aI[1], af0, w1_); MFV(aJ[0], af0, w2_);
    MFV(aJ[1], af0, w3_); MFV(aO[0], af0, w4_); MFV(aO[1], af0, w5_);
    // kk7 weight reads (reuse regs)
    DSR(w0_, wa7, 0);     DSR(w1_, wa7, 1280);  DSR(w2_, wa7, 20480);
    DSR(w3_, wa7, 21760); DSR(w4_, wa7, 40960); DSR(w5_, wa7, 42240);
    WLG(0);
    MFV(aI[0], af1, w0_); MFV(aI[1], af1, w1_); MFV(aJ[0], af1, w2_);
    MFV(aJ[1], af1, w3_); MFV(aO[0], af1, w4_); MFV(aO[1], af1, w5_);
    // fence: MFMA writes acc -> VALU reads (16 idle cycles)
    asm volatile("s_nop 7\n\ts_nop 7"
                 : "+v"(aI[0]), "+v"(aI[1]), "+v"(aJ[0]), "+v"(aJ[1]),
                   "+v"(aO[0]), "+v"(aO[1]));

    // gates: i=sig, j=tanh, o=sig; c=(1-i)c + i*j; h=tanh(c)*o
    u16 hv[2][4];
    float hfv[2][4];
#pragma unroll
    for (int nt = 0; nt < 2; ++nt)
#pragma unroll
      for (int rr = 0; rr < 4; ++rr) {
        const float iv = sigm(aI[nt][rr]);
        const float jv = tanh_f(aJ[nt][rr]);
        const float ov = sigm(aO[nt][rr]);
        const float c = (1.f - iv) * cst[nt][rr] + iv * jv;
        cst[nt][rr] = c;
        const float h = tanh_f(c) * ov;
        hfv[nt][rr] = h;
        hv[nt][rr] = f2b(h);
      }

    // emit ys[tt] and h(t+1) into the OTHER h buffer
#pragma unroll
    for (int nt = 0; nt < 2; ++nt) {
      const int col = wid * 32 + nt * 16 + l15;
#pragma unroll
      for (int rr = 0; rr < 4; ++rr) {
        ysp[(size_t)rr * 512 + nt * 16] = hv[nt][rr];
        h_lds[par ^ 1][(quad * 4 + rr) * 264 + col] = hv[nt][rr];
      }
    }

    if (t == 1023) {
#pragma unroll
      for (int nt = 0; nt < 2; ++nt) {
        const int col = wid * 32 + nt * 16 + l15;
#pragma unroll
        for (int rr = 0; rr < 4; ++rr) {
          const int b = bh * 16 + quad * 4 + rr;
          hn[dir * 8192 + b * 256 + col] = hfv[nt][rr];
          cn[dir * 8192 + b * 256 + col] = cst[nt][rr];
        }
      }
      break;
    }

    __syncthreads();
    par ^= 1;
    zp += zstep;
    ysp += ystep;
  }
}

// ---------------------------------------------------------------------------
extern "C" void kernel_launch(void* const* d_in, const int* in_sizes, int n_in,
                              void* d_out, int out_size, void* d_ws, size_t ws_size,
                              hipStream_t stream) {
  const float* x = (const float*)d_in[0];
  const float* h0 = (const float*)d_in[1];
  const float* c0 = (const float*)d_in[2];
  const float* Wf0 = (const float*)d_in[3];
  const float* bf0 = (const float*)d_in[4];
  const float* Wb0 = (const float*)d_in[5];
  const float* bb0 = (const float*)d_in[6];
  const float* Wf1 = (const float*)d_in[7];
  const float* bf1 = (const float*)d_in[8];
  const float* Wb1 = (const float*)d_in[9];
  const float* bb1 = (const float*)d_in[10];
  const float* Wf2 = (const float*)d_in[11];
  const float* bf2 = (const float*)d_in[12];
  const float* Wb2 = (const float*)d_in[13];
  const float* bb2 = (const float*)d_in[14];
  const float* Whw = (const float*)d_in[15];
  const float* bhw = (const float*)d_in[16];
  float* out = (float*)d_out;  // fp32 (reference output dtype)

  // ws layout (~182.5 MiB)
  u16* Zf = (u16*)d_ws;                // 25165824 u16 (fp16 row-major, 48 MiB)
  u16* Zb = Zf + 25165824;             // 48 MiB
  u16* bufA = Zb + 25165824;           // 16777216 bf16 (32 MiB)
  u16* bufB = bufA + 16777216;         // 16777216 bf16 (32 MiB)
  u16* xb = bufB + 16777216;           // 8388608 bf16 (16 MiB)
  u16* Wt = xb + 8388608;              // 3407872 bf16 (6.5 MiB)

  u16* Wt0f = Wt;
  u16* Wt0b = Wt0f + 393216;
  u16* Wt1f = Wt0b + 393216;
  u16* Wt1b = Wt1f + 589824;
  u16* Wt2f = Wt1b + 589824;
  u16* Wt2b = Wt2f + 589824;
  u16* Wthw = Wt2b + 589824;

  float* hnb = out + 16777216;  // h_n [6][32][256] fp32
  float* cnb = hnb + 49152;     // c_n [6][32][256] fp32

  k_convert<<<8192, 256, 0, stream>>>(x, xb, 2097152);
  k_transpose<<<dim3(2304, 7), 256, 0, stream>>>(Wf0, Wb0, Wf1, Wb1, Wf2, Wb2, Whw, Wt);

  // layer 0 (Kin=256, Wt pitch 512): ys -> bufA (no highway)
  k_pregemm<<<dim3(256, 6, 2), 256, 0, stream>>>(xb, 256, Wt0f, Wt0b, 512, bf0, bb0, Zf, Zb);
  k_scan<<<dim3(4), 512, 0, stream>>>(Zf, Zb, Wt0f, Wt0b, 512, 256, h0, c0, bufA,
                                      hnb + 0 * 8192, cnb + 0 * 8192);

  // layer 1 (Kin=512, pitch 768): ys -> bufB; highway(Ys=bufB, Cur=bufA) -> bufA (bf16)
  k_pregemm<<<dim3(256, 6, 2), 256, 0, stream>>>(bufA, 512, Wt1f, Wt1b, 768, bf1, bb1, Zf, Zb);
  k_scan<<<dim3(4), 512, 0, stream>>>(Zf, Zb, Wt1f, Wt1b, 768, 512, h0, c0, bufB,
                                      hnb + 2 * 8192, cnb + 2 * 8192);
  k_highway<<<dim3(256, 4), 256, 0, stream>>>(bufB, bufA, Wthw, bhw, bufA, (float*)nullptr);

  // layer 2: ys -> bufB; highway(Ys=bufB, Cur=bufA) -> out (fp32, final)
  k_pregemm<<<dim3(256, 6, 2), 256, 0, stream>>>(bufA, 512, Wt2f, Wt2b, 768, bf2, bb2, Zf, Zb);
  k_scan<<<dim3(4), 512, 0, stream>>>(Zf, Zb, Wt2f, Wt2b, 768, 512, h0, c0, bufB,
                                      hnb + 4 * 8192, cnb + 4 * 8192);
  k_highway<<<dim3(256, 4), 256, 0, stream>>>(bufB, bufA, Wthw, bhw, (u16*)nullptr, out);
}

// Round 3
// 7445.502 us; speedup vs baseline: 1.5143x; 1.5143x over previous
//
#include <hip/hip_runtime.h>
#include <stdint.h>

// BiLSTM (3-layer, bidirectional, 3-gate custom cell, highway) for MI355X.
//
// R11: the scan is VALU/transcendental-bound, not weight-bound.
// Post-mortem R10: AGPR+LDS weight pin landed (VGPR 116, LDS 139776) and
// changed NOTHING -- 3.57 ms scan across 4 different weight schemes.
// VALUBusy on the 4 active CUs ~70% vs MfmaUtil 18%: the ~8 gate-elements
// per thread (sigm/tanh = quarter-rate v_exp/v_rcp) dominate the step.
// Fix: (a) split batch 16->8 rows/block (grid 4->8 blocks = 8 CUs);
// (b) with m=16 MFMA only rows 0-7 are real -- combine the (nt0,nt1)
// C-fragments via v_permlane32_swap_b32 so lanes 32-63 take nt1's valid
// rows: all 64 lanes hold valid gates, 4 h-elements/thread (was 8);
// (c) Z added AFTER the swap (12 asm-prefetched loads in final layout),
// SrcC comes from a persistent zero vector (no per-step h2f/movs init).
// Weight residency (AGPR a0..a143 + w_lds kk6,7) unchanged from R10.
// Outputs fp32.

typedef unsigned short u16;
typedef unsigned int u32;
typedef unsigned long long u64;
typedef __attribute__((ext_vector_type(8))) short short8;   // 8 bf16
typedef __attribute__((ext_vector_type(4))) float f32x4;
typedef __attribute__((ext_vector_type(4))) u32 u32x4;

#define MFMA16(a, b, c) __builtin_amdgcn_mfma_f32_16x16x32_bf16((a), (b), (c), 0, 0, 0)

__device__ __forceinline__ float b2f(u16 u) {
  u32 v = ((u32)u) << 16;
  return __builtin_bit_cast(float, v);
}
__device__ __forceinline__ u16 f2b(float f) {  // round-to-nearest-even
  u32 u = __builtin_bit_cast(u32, f);
  u32 r = u + 0x7FFFu + ((u >> 16) & 1u);
  return (u16)(r >> 16);
}
__device__ __forceinline__ u16 f2h(float f) {  // fp32 -> fp16 bits
  return __builtin_bit_cast(u16, (_Float16)f);
}
__device__ __forceinline__ float h2f(u16 u) {  // fp16 bits -> fp32
  return (float)__builtin_bit_cast(_Float16, u);
}
// Overflow-proof activations: exp args always <= 0 -> no inf/NaN possible.
__device__ __forceinline__ float sigm(float x) {
  const float q = __expf(-fabsf(x));
  const float r = 1.f / (1.f + q);
  return x >= 0.f ? r : 1.f - r;
}
__device__ __forceinline__ float tanh_f(float x) {
  const float q = __expf(-2.f * fabsf(x));
  const float t = (1.f - q) / (1.f + q);
  return x >= 0.f ? t : -t;
}

// ---------------------------------------------------------------------------
// Convert x (fp32) -> bf16, vectorized float4.
// ---------------------------------------------------------------------------
__global__ void k_convert(const float* __restrict__ src, u16* __restrict__ dst, int n4) {
  int i = blockIdx.x * 256 + threadIdx.x;
  if (i < n4) {
    float4 v = ((const float4*)src)[i];
    ushort4 o;
    o.x = f2b(v.x); o.y = f2b(v.y); o.z = f2b(v.z); o.w = f2b(v.w);
    ((ushort4*)dst)[i] = o;
  }
}

// ---------------------------------------------------------------------------
// Transpose + convert all weight matrices (fp32 W[R][C] -> bf16 Wt[C][R]).
// ---------------------------------------------------------------------------
__global__ void k_transpose(const float* __restrict__ w0, const float* __restrict__ w1,
                            const float* __restrict__ w2, const float* __restrict__ w3,
                            const float* __restrict__ w4, const float* __restrict__ w5,
                            const float* __restrict__ w6, u16* __restrict__ wt) {
  int z = blockIdx.y;
  const float* src;
  int R, C;
  size_t off;
  switch (z) {
    case 0: src = w0; R = 512; C = 768; off = 0u; break;
    case 1: src = w1; R = 512; C = 768; off = 393216u; break;
    case 2: src = w2; R = 768; C = 768; off = 786432u; break;
    case 3: src = w3; R = 768; C = 768; off = 1376256u; break;
    case 4: src = w4; R = 768; C = 768; off = 1966080u; break;
    case 5: src = w5; R = 768; C = 768; off = 2555904u; break;
    default: src = w6; R = 512; C = 512; off = 3145728u; break;
  }
  size_t total = (size_t)R * C;
  size_t e = (size_t)blockIdx.x * 256 + threadIdx.x;
  if (e < total) {
    int cc = (int)(e / (size_t)R);
    int rr = (int)(e - (size_t)cc * R);
    wt[off + e] = f2b(src[(size_t)rr * C + cc]);
  }
}

// ---------------------------------------------------------------------------
// Pre-GEMM: Z[m][n] = fp16( sum_k A[m][k]*Wt[n][k] + bias[n] )  (row-major)
// A bf16 [32768][Ka]; grid=(256, 6, 2[dir]); block=256; 128x128 tile.
// EXACT R5 code (passing).
// ---------------------------------------------------------------------------
__launch_bounds__(256) __global__
void k_pregemm(const u16* __restrict__ A, int Ka,
               const u16* __restrict__ WtF, const u16* __restrict__ WtB, int Kb,
               const float* __restrict__ biasF, const float* __restrict__ biasB,
               u16* __restrict__ ZF, u16* __restrict__ ZB) {
  const int dir = blockIdx.z;
  const u16* Bt = dir ? WtB : WtF;
  const float* bias = dir ? biasB : biasF;
  u16* Z = dir ? ZB : ZF;
  const int m0 = blockIdx.x * 128;
  const int n0 = blockIdx.y * 128;

  __shared__ u16 lA[128 * 40];
  __shared__ u16 lB[128 * 40];

  const int tid = threadIdx.x;
  const int wave = tid >> 6, lane = tid & 63, quad = lane >> 4, l15 = lane & 15;
  const int wy = wave >> 1, wx = wave & 1;
  const int r = tid >> 2, kc = tid & 3;

  f32x4 acc[4][4];
#pragma unroll
  for (int i = 0; i < 4; ++i)
#pragma unroll
    for (int j = 0; j < 4; ++j)
#pragma unroll
      for (int k = 0; k < 4; ++k) acc[i][j][k] = 0.f;

  const int nk = Ka >> 5;
  for (int kk = 0; kk < nk; ++kk) {
    const u16* Ap = A + (size_t)(m0 + r) * Ka + kk * 32 + kc * 8;
    uint4 a0 = *(const uint4*)Ap;
    uint4 a1 = *(const uint4*)(Ap + (size_t)64 * Ka);
    const u16* Bp = Bt + (size_t)(n0 + r) * Kb + kk * 32 + kc * 8;
    uint4 b0 = *(const uint4*)Bp;
    uint4 b1 = *(const uint4*)(Bp + (size_t)64 * Kb);
    __syncthreads();
    *(uint4*)&lA[r * 40 + kc * 8] = a0;
    *(uint4*)&lA[(r + 64) * 40 + kc * 8] = a1;
    *(uint4*)&lB[r * 40 + kc * 8] = b0;
    *(uint4*)&lB[(r + 64) * 40 + kc * 8] = b1;
    __syncthreads();
    short8 af[4], bf[4];
#pragma unroll
    for (int mt = 0; mt < 4; ++mt)
      af[mt] = *(const short8*)&lA[(wy * 64 + mt * 16 + l15) * 40 + quad * 8];
#pragma unroll
    for (int nt = 0; nt < 4; ++nt)
      bf[nt] = *(const short8*)&lB[(wx * 64 + nt * 16 + l15) * 40 + quad * 8];
#pragma unroll
    for (int mt = 0; mt < 4; ++mt)
#pragma unroll
      for (int nt = 0; nt < 4; ++nt) acc[mt][nt] = MFMA16(af[mt], bf[nt], acc[mt][nt]);
  }

#pragma unroll
  for (int nt = 0; nt < 4; ++nt) {
    const int col = n0 + wx * 64 + nt * 16 + l15;
    const float bv = bias[col];
#pragma unroll
    for (int mt = 0; mt < 4; ++mt) {
      const int mbase = m0 + wy * 64 + mt * 16 + quad * 4;
#pragma unroll
      for (int rr = 0; rr < 4; ++rr)
        Z[(size_t)(mbase + rr) * 768 + col] = f2h(acc[mt][nt][rr] + bv);
    }
  }
}

// ---------------------------------------------------------------------------
// Highway: g = sigmoid(ys @ Wt_hw^T + b_hw); v = g*ys + (1-g)*cur.
// Dual outputs: Outb (bf16, may be null) / OutF (fp32 final, may be null).
// Cur/Outb may alias (owner-thread read-before-write); Ys never aliases.
// EXACT R5 code (passing).
// ---------------------------------------------------------------------------
__launch_bounds__(256) __global__
void k_highway(const u16* __restrict__ Ys, const u16* Cur,
               const u16* __restrict__ Wt, const float* __restrict__ bias,
               u16* Outb, float* OutF) {
  const int m0 = blockIdx.x * 128;
  const int n0 = blockIdx.y * 128;

  __shared__ u16 lA[128 * 40];
  __shared__ u16 lB[128 * 40];

  const int tid = threadIdx.x;
  const int wave = tid >> 6, lane = tid & 63, quad = lane >> 4, l15 = lane & 15;
  const int wy = wave >> 1, wx = wave & 1;
  const int r = tid >> 2, kc = tid & 3;

  f32x4 acc[4][4];
#pragma unroll
  for (int i = 0; i < 4; ++i)
#pragma unroll
    for (int j = 0; j < 4; ++j)
#pragma unroll
      for (int k = 0; k < 4; ++k) acc[i][j][k] = 0.f;

  for (int kk = 0; kk < 16; ++kk) {
    const u16* Ap = Ys + (size_t)(m0 + r) * 512 + kk * 32 + kc * 8;
    uint4 a0 = *(const uint4*)Ap;
    uint4 a1 = *(const uint4*)(Ap + (size_t)64 * 512);
    const u16* Bp = Wt + (size_t)(n0 + r) * 512 + kk * 32 + kc * 8;
    uint4 b0 = *(const uint4*)Bp;
    uint4 b1 = *(const uint4*)(Bp + (size_t)64 * 512);
    __syncthreads();
    *(uint4*)&lA[r * 40 + kc * 8] = a0;
    *(uint4*)&lA[(r + 64) * 40 + kc * 8] = a1;
    *(uint4*)&lB[r * 40 + kc * 8] = b0;
    *(uint4*)&lB[(r + 64) * 40 + kc * 8] = b1;
    __syncthreads();
    short8 af[4], bf[4];
#pragma unroll
    for (int mt = 0; mt < 4; ++mt)
      af[mt] = *(const short8*)&lA[(wy * 64 + mt * 16 + l15) * 40 + quad * 8];
#pragma unroll
    for (int nt = 0; nt < 4; ++nt)
      bf[nt] = *(const short8*)&lB[(wx * 64 + nt * 16 + l15) * 40 + quad * 8];
#pragma unroll
    for (int mt = 0; mt < 4; ++mt)
#pragma unroll
      for (int nt = 0; nt < 4; ++nt) acc[mt][nt] = MFMA16(af[mt], bf[nt], acc[mt][nt]);
  }

#pragma unroll
  for (int nt = 0; nt < 4; ++nt) {
    const int col = n0 + wx * 64 + nt * 16 + l15;
    const float bv = bias[col];
#pragma unroll
    for (int mt = 0; mt < 4; ++mt) {
      const int mbase = m0 + wy * 64 + mt * 16 + quad * 4;
#pragma unroll
      for (int rr = 0; rr < 4; ++rr) {
        const size_t idx = (size_t)(mbase + rr) * 512 + col;
        const float g = sigm(acc[mt][nt][rr] + bv);
        const float v = g * b2f(Ys[idx]) + (1.f - g) * b2f(Cur[idx]);
        if (Outb) Outb[idx] = f2b(v);
        if (OutF) OutF[idx] = v;
      }
    }
  }
}

// ---------------------------------------------------------------------------
// Scan: 8 blocks (dir = bx>>2, batch-group bg = bx&3 -> rows bg*8..bg*8+7),
// block=512 (8 waves). Weight residency per R10 (AGPR kk0-5 + LDS kk6-7).
// m=16 MFMA rows 8-15 are dead; v_permlane32_swap_b32 merges (nt0,nt1)
// C-frags so all 64 lanes carry valid gates (4 h-elements/thread).
// Z prefetched via asm global_load_ushort at loop top, added post-swap.
// ---------------------------------------------------------------------------

// pin one 16B weight fragment into AGPRs A0..A3
#define LP(A0, A1, A2, A3, G, NT, KK)                                              \
  do {                                                                             \
    short8 _w = *(const short8*)(Wt +                                              \
        (size_t)((G)*256 + wid * 32 + (NT)*16 + l15) * wt_pitch + koff +           \
        (KK)*32 + quad * 8);                                                       \
    u32x4 _u = __builtin_bit_cast(u32x4, _w);                                      \
    asm volatile("v_accvgpr_write_b32 a" #A0 ", %0\n\t"                            \
                 "v_accvgpr_write_b32 a" #A1 ", %1\n\t"                            \
                 "v_accvgpr_write_b32 a" #A2 ", %2\n\t"                            \
                 "v_accvgpr_write_b32 a" #A3 ", %3"                                \
                 :: "v"(_u[0]), "v"(_u[1]), "v"(_u[2]), "v"(_u[3])                 \
                 : "a" #A0, "a" #A1, "a" #A2, "a" #A3);                            \
  } while (0)

// D += A * B, B hard-coded AGPR range (accumulating form)
#define MFA(LO, HI, ACC, AF)                                                       \
  asm volatile("v_mfma_f32_16x16x32_bf16 %0, %1, a[" #LO ":" #HI "], %0"           \
               : "+v"(ACC) : "v"(AF))

// D = A * B + Z (non-accumulating first MFMA; Z = persistent zero vector)
#define MFA0(LO, HI, ACC, AF, ZZ)                                                  \
  asm volatile("v_mfma_f32_16x16x32_bf16 %0, %1, a[" #LO ":" #HI "], %2"           \
               : "=&v"(ACC) : "v"(AF), "v"(ZZ))

// D += A * B, B from VGPR (LDS-resident slices)
#define MFV(ACC, AF, BW)                                                           \
  asm volatile("v_mfma_f32_16x16x32_bf16 %0, %1, %2, %0"                           \
               : "+v"(ACC) : "v"(AF), "v"(BW))

#define DSR(DST, ADDR, OFF)                                                        \
  asm volatile("ds_read_b128 %0, %1 offset:" #OFF : "=v"(DST) : "v"(ADDR))

#define WLG(N) asm volatile("s_waitcnt lgkmcnt(" #N ")")

// prefetch one fp16 Z element (zero-extended into a u32 VGPR)
#define GL16(DST, ADDR, OFF)                                                       \
  asm volatile("global_load_ushort %0, %1, off offset:" #OFF                       \
               : "=v"(DST) : "v"(ADDR))

// swap upper half of A with lower half of B: A' = {A[0:31], B[0:31]}
#define PSWAP(A, B)                                                                \
  asm volatile("s_nop 1\n\tv_permlane32_swap_b32 %0, %1" : "+v"(A), "+v"(B))

__global__ __attribute__((amdgpu_flat_work_group_size(512, 512), amdgpu_waves_per_eu(2, 2)))
void k_scan(const u16* __restrict__ ZF, const u16* __restrict__ ZB,
            const u16* __restrict__ WtF, const u16* __restrict__ WtB,
            int wt_pitch, int koff,
            const float* __restrict__ h0, const float* __restrict__ c0,
            u16* __restrict__ ys,            // bf16 [32768][512]; fwd 0-255, bwd 256-511
            float* __restrict__ hn, float* __restrict__ cn) {  // fp32, + dir*8192
  const int tid = threadIdx.x;
  const int wid = tid >> 6, lane = tid & 63, quad = lane >> 4, l15 = lane & 15;
  const int hl = lane >> 5;        // 0: lanes 0-31 (nt0), 1: lanes 32-63 (nt1)
  const int q2 = quad & 1;         // row group within the 8-row batch slice
  const int dir = blockIdx.x >> 2, bg = blockIdx.x & 3;
  const u16* Z = dir ? ZB : ZF;
  const u16* Wt = dir ? WtB : WtF;

  __shared__ u16 h_lds[2][16 * 264];   // double-buffered h(t) [b][k], pitch 264
  __shared__ u16 w_lds[2 * 768 * 40];  // W_h kk=6,7 slices, pitch 40 (80B rows)

  // ---- pin kk=0..5 weight fragments into a0..a143 (col n = g*256+wid*32+nt*16+l15)
  LP(0,1,2,3, 0,0,0);     LP(4,5,6,7, 0,0,1);     LP(8,9,10,11, 0,0,2);
  LP(12,13,14,15, 0,0,3); LP(16,17,18,19, 0,0,4); LP(20,21,22,23, 0,0,5);
  LP(24,25,26,27, 0,1,0); LP(28,29,30,31, 0,1,1); LP(32,33,34,35, 0,1,2);
  LP(36,37,38,39, 0,1,3); LP(40,41,42,43, 0,1,4); LP(44,45,46,47, 0,1,5);
  LP(48,49,50,51, 1,0,0); LP(52,53,54,55, 1,0,1); LP(56,57,58,59, 1,0,2);
  LP(60,61,62,63, 1,0,3); LP(64,65,66,67, 1,0,4); LP(68,69,70,71, 1,0,5);
  LP(72,73,74,75, 1,1,0); LP(76,77,78,79, 1,1,1); LP(80,81,82,83, 1,1,2);
  LP(84,85,86,87, 1,1,3); LP(88,89,90,91, 1,1,4); LP(92,93,94,95, 1,1,5);
  LP(96,97,98,99, 2,0,0);    LP(100,101,102,103, 2,0,1); LP(104,105,106,107, 2,0,2);
  LP(108,109,110,111, 2,0,3); LP(112,113,114,115, 2,0,4); LP(116,117,118,119, 2,0,5);
  LP(120,121,122,123, 2,1,0); LP(124,125,126,127, 2,1,1); LP(128,129,130,131, 2,1,2);
  LP(132,133,134,135, 2,1,3); LP(136,137,138,139, 2,1,4); LP(140,141,142,143, 2,1,5);

  // ---- fill w_lds with kk=6,7 slices: dst [slice][col*40 + q*8], 16B chunks
  for (int i = tid; i < 6144; i += 512) {
    const int slice = (i >= 3072) ? 1 : 0;
    const int rem = i - slice * 3072;
    const int col = rem >> 2, q = rem & 3;
    *(uint4*)&w_lds[slice * 30720 + col * 40 + q * 8] =
        *(const uint4*)(Wt + (size_t)col * wt_pitch + koff + 192 + slice * 32 + q * 8);
  }

  // ---- init h_lds: buf0 rows 0-7 = h0 broadcast, everything else zero
  //      (rows 8-15 of BOTH buffers must stay zero: they feed dead MFMA rows)
  for (int i = tid; i < 8448; i += 512) {
    const int buf = (i >= 4224) ? 1 : 0;
    const int rem = i - buf * 4224;
    const int r = rem / 264, k = rem - r * 264;
    u16 v = (buf == 0 && r < 8 && k < 256) ? f2b(h0[k]) : (u16)0;
    ((u16*)h_lds)[i] = v;
  }
  // combined-lane column and per-thread cell state (4 rows, col-broadcast c0)
  const int colc = wid * 32 + hl * 16 + l15;
  float cst[4];
  {
    const float cv = c0[colc];
#pragma unroll
    for (int rr = 0; rr < 4; ++rr) cst[rr] = cv;
  }
  __syncthreads();

  // ---- LDS byte-address bases (low 32 bits of LDS generic addr = offset)
  const u32 hbase = (u32)(uintptr_t)&h_lds[0][0] + (u32)((l15 * 264 + quad * 8) * 2);
  const u32 wa6 = (u32)(uintptr_t)&w_lds[0] + (u32)(((wid * 32 + l15) * 40 + quad * 8) * 2);
  const u32 wa7 = wa6 + 61440u;  // + 768*40*2

  // ---- running per-lane pointers (post-swap layout: row = bg*8+q2*4+rr)
  const size_t zlane = ((size_t)bg * 8 + q2 * 4) * 768 + colc;
  const u16* zp = Z + zlane + (dir ? (size_t)1023 * 24576 : (size_t)0);
  const ptrdiff_t zstep = dir ? -(ptrdiff_t)24576 : (ptrdiff_t)24576;
  const size_t yslane = ((size_t)bg * 8 + q2 * 4) * 512 + (size_t)dir * 256 + colc;
  u16* ysp = ys + yslane + (dir ? (size_t)1023 * 16384 : (size_t)0);
  const ptrdiff_t ystep = dir ? -(ptrdiff_t)16384 : (ptrdiff_t)16384;

  const f32x4 zv = {0.f, 0.f, 0.f, 0.f};  // persistent MFMA SrcC zeros

  int par = 0;
#pragma unroll 1
  for (int t = 0; t < 1024; ++t) {
    // ---- prefetch Z (fp16, final post-swap layout): rows rr, gates g
    u32 zr[3][4];
    {
      const u16* zb0 = zp;            // rows 0,1 of this thread's 4
      const u16* zb1 = zp + 1536;     // rows 2,3
      GL16(zr[0][0], zb0, 0);    GL16(zr[1][0], zb0, 512);  GL16(zr[2][0], zb0, 1024);
      GL16(zr[0][1], zb0, 1536); GL16(zr[1][1], zb0, 2048); GL16(zr[2][1], zb0, 2560);
      GL16(zr[0][2], zb1, 0);    GL16(zr[1][2], zb1, 512);  GL16(zr[2][2], zb1, 1024);
      GL16(zr[0][3], zb1, 1536); GL16(zr[1][3], zb1, 2048); GL16(zr[2][3], zb1, 2560);
    }

    const u32 ha = hbase + (par ? 8448u : 0u);
    short8 af0, af1;
    DSR(af0, ha, 0);
    DSR(af1, ha, 64);

    f32x4 aI[2], aJ[2], aO[2];
    // kk0 (af0): non-accumulating, SrcC = zeros
    WLG(1);
    MFA0(0,3, aI[0], af0, zv);   MFA0(24,27, aI[1], af0, zv);
    MFA0(48,51, aJ[0], af0, zv); MFA0(72,75, aJ[1], af0, zv);
    MFA0(96,99, aO[0], af0, zv); MFA0(120,123, aO[1], af0, zv);
    DSR(af0, ha, 128);
    // kk1 (af1)
    WLG(1);
    MFA(4,7, aI[0], af1);   MFA(28,31, aI[1], af1);  MFA(52,55, aJ[0], af1);
    MFA(76,79, aJ[1], af1); MFA(100,103, aO[0], af1); MFA(124,127, aO[1], af1);
    DSR(af1, ha, 192);
    // kk2 (af0)
    WLG(1);
    MFA(8,11, aI[0], af0);  MFA(32,35, aI[1], af0);  MFA(56,59, aJ[0], af0);
    MFA(80,83, aJ[1], af0); MFA(104,107, aO[0], af0); MFA(128,131, aO[1], af0);
    DSR(af0, ha, 256);
    // kk3 (af1)
    WLG(1);
    MFA(12,15, aI[0], af1); MFA(36,39, aI[1], af1);  MFA(60,63, aJ[0], af1);
    MFA(84,87, aJ[1], af1); MFA(108,111, aO[0], af1); MFA(132,135, aO[1], af1);
    DSR(af1, ha, 320);
    // kk4 (af0)
    WLG(1);
    MFA(16,19, aI[0], af0); MFA(40,43, aI[1], af0);  MFA(64,67, aJ[0], af0);
    MFA(88,91, aJ[1], af0); MFA(112,115, aO[0], af0); MFA(136,139, aO[1], af0);
    DSR(af0, ha, 384);
    // kk5 (af1)
    WLG(1);
    MFA(20,23, aI[0], af1); MFA(44,47, aI[1], af1);  MFA(68,71, aJ[0], af1);
    MFA(92,95, aJ[1], af1); MFA(116,119, aO[0], af1); MFA(140,143, aO[1], af1);
    // issue kk6 weight reads + kk7 afrag
    short8 w0_, w1_, w2_, w3_, w4_, w5_;
    DSR(w0_, wa6, 0);     DSR(w1_, wa6, 1280);  DSR(w2_, wa6, 20480);
    DSR(w3_, wa6, 21760); DSR(w4_, wa6, 40960); DSR(w5_, wa6, 42240);
    DSR(af1, ha, 448);
    // kk6 (af0 from offset 384, weights from LDS slice 0)
    WLG(1);
    MFV(aI[0], af0, w0_); MFV(aI[1], af0, w1_); MFV(aJ[0], af0, w2_);
    MFV(aJ[1], af0, w3_); MFV(aO[0], af0, w4_); MFV(aO[1], af0, w5_);
    // kk7 weight reads (reuse regs)
    DSR(w0_, wa7, 0);     DSR(w1_, wa7, 1280);  DSR(w2_, wa7, 20480);
    DSR(w3_, wa7, 21760); DSR(w4_, wa7, 40960); DSR(w5_, wa7, 42240);
    WLG(0);
    MFV(aI[0], af1, w0_); MFV(aI[1], af1, w1_); MFV(aJ[0], af1, w2_);
    MFV(aJ[1], af1, w3_); MFV(aO[0], af1, w4_); MFV(aO[1], af1, w5_);
    // fence: MFMA writes acc -> VALU reads (16 idle cycles)
    asm volatile("s_nop 7\n\ts_nop 7"
                 : "+v"(aI[0]), "+v"(aI[1]), "+v"(aJ[0]), "+v"(aJ[1]),
                   "+v"(aO[0]), "+v"(aO[1]));
    // Z prefetch must be home before the adds below
    asm volatile("s_waitcnt vmcnt(0)");
    __builtin_amdgcn_sched_barrier(0);

    // ---- merge nt1's valid rows into lanes 32-63, add Z (bias included)
    float gI[4], gJ[4], gO[4];
#pragma unroll
    for (int rr = 0; rr < 4; ++rr) {
      float s0, s1;
      s0 = aI[0][rr]; s1 = aI[1][rr]; PSWAP(s0, s1);
      gI[rr] = s0 + h2f((u16)zr[0][rr]);
      s0 = aJ[0][rr]; s1 = aJ[1][rr]; PSWAP(s0, s1);
      gJ[rr] = s0 + h2f((u16)zr[1][rr]);
      s0 = aO[0][rr]; s1 = aO[1][rr]; PSWAP(s0, s1);
      gO[rr] = s0 + h2f((u16)zr[2][rr]);
    }

    // gates: i=sig, j=tanh, o=sig; c=(1-i)c + i*j; h=tanh(c)*o
    u16 hv[4];
    float hfv[4];
#pragma unroll
    for (int rr = 0; rr < 4; ++rr) {
      const float iv = sigm(gI[rr]);
      const float jv = tanh_f(gJ[rr]);
      const float ov = sigm(gO[rr]);
      const float c = (1.f - iv) * cst[rr] + iv * jv;
      cst[rr] = c;
      const float h = tanh_f(c) * ov;
      hfv[rr] = h;
      hv[rr] = f2b(h);
    }

    // emit ys[tt]
#pragma unroll
    for (int rr = 0; rr < 4; ++rr) ysp[(size_t)rr * 512] = hv[rr];

    if (t == 1023) {
#pragma unroll
      for (int rr = 0; rr < 4; ++rr) {
        const int b = bg * 8 + q2 * 4 + rr;
        hn[dir * 8192 + b * 256 + colc] = hfv[rr];
        cn[dir * 8192 + b * 256 + colc] = cst[rr];
      }
      break;
    }

    // write h(t+1) rows 0-7 into the OTHER buffer; one barrier
#pragma unroll
    for (int rr = 0; rr < 4; ++rr)
      h_lds[par ^ 1][(q2 * 4 + rr) * 264 + colc] = hv[rr];
    __syncthreads();
    par ^= 1;
    zp += zstep;
    ysp += ystep;
  }
}

// ---------------------------------------------------------------------------
extern "C" void kernel_launch(void* const* d_in, const int* in_sizes, int n_in,
                              void* d_out, int out_size, void* d_ws, size_t ws_size,
                              hipStream_t stream) {
  const float* x = (const float*)d_in[0];
  const float* h0 = (const float*)d_in[1];
  const float* c0 = (const float*)d_in[2];
  const float* Wf0 = (const float*)d_in[3];
  const float* bf0 = (const float*)d_in[4];
  const float* Wb0 = (const float*)d_in[5];
  const float* bb0 = (const float*)d_in[6];
  const float* Wf1 = (const float*)d_in[7];
  const float* bf1 = (const float*)d_in[8];
  const float* Wb1 = (const float*)d_in[9];
  const float* bb1 = (const float*)d_in[10];
  const float* Wf2 = (const float*)d_in[11];
  const float* bf2 = (const float*)d_in[12];
  const float* Wb2 = (const float*)d_in[13];
  const float* bb2 = (const float*)d_in[14];
  const float* Whw = (const float*)d_in[15];
  const float* bhw = (const float*)d_in[16];
  float* out = (float*)d_out;  // fp32 (reference output dtype)

  // ws layout (~182.5 MiB)
  u16* Zf = (u16*)d_ws;                // 25165824 u16 (fp16 row-major, 48 MiB)
  u16* Zb = Zf + 25165824;             // 48 MiB
  u16* bufA = Zb + 25165824;           // 16777216 bf16 (32 MiB)
  u16* bufB = bufA + 16777216;         // 16777216 bf16 (32 MiB)
  u16* xb = bufB + 16777216;           // 8388608 bf16 (16 MiB)
  u16* Wt = xb + 8388608;              // 3407872 bf16 (6.5 MiB)

  u16* Wt0f = Wt;
  u16* Wt0b = Wt0f + 393216;
  u16* Wt1f = Wt0b + 393216;
  u16* Wt1b = Wt1f + 589824;
  u16* Wt2f = Wt1b + 589824;
  u16* Wt2b = Wt2f + 589824;
  u16* Wthw = Wt2b + 589824;

  float* hnb = out + 16777216;  // h_n [6][32][256] fp32
  float* cnb = hnb + 49152;     // c_n [6][32][256] fp32

  k_convert<<<8192, 256, 0, stream>>>(x, xb, 2097152);
  k_transpose<<<dim3(2304, 7), 256, 0, stream>>>(Wf0, Wb0, Wf1, Wb1, Wf2, Wb2, Whw, Wt);

  // layer 0 (Kin=256, Wt pitch 512): ys -> bufA (no highway)
  k_pregemm<<<dim3(256, 6, 2), 256, 0, stream>>>(xb, 256, Wt0f, Wt0b, 512, bf0, bb0, Zf, Zb);
  k_scan<<<dim3(8), 512, 0, stream>>>(Zf, Zb, Wt0f, Wt0b, 512, 256, h0, c0, bufA,
                                      hnb + 0 * 8192, cnb + 0 * 8192);

  // layer 1 (Kin=512, pitch 768): ys -> bufB; highway(Ys=bufB, Cur=bufA) -> bufA (bf16)
  k_pregemm<<<dim3(256, 6, 2), 256, 0, stream>>>(bufA, 512, Wt1f, Wt1b, 768, bf1, bb1, Zf, Zb);
  k_scan<<<dim3(8), 512, 0, stream>>>(Zf, Zb, Wt1f, Wt1b, 768, 512, h0, c0, bufB,
                                      hnb + 2 * 8192, cnb + 2 * 8192);
  k_highway<<<dim3(256, 4), 256, 0, stream>>>(bufB, bufA, Wthw, bhw, bufA, (float*)nullptr);

  // layer 2: ys -> bufB; highway(Ys=bufB, Cur=bufA) -> out (fp32, final)
  k_pregemm<<<dim3(256, 6, 2), 256, 0, stream>>>(bufA, 512, Wt2f, Wt2b, 768, bf2, bb2, Zf, Zb);
  k_scan<<<dim3(8), 512, 0, stream>>>(Zf, Zb, Wt2f, Wt2b, 768, 512, h0, c0, bufB,
                                      hnb + 4 * 8192, cnb + 4 * 8192);
  k_highway<<<dim3(256, 4), 256, 0, stream>>>(bufB, bufA, Wthw, bhw, (u16*)nullptr, out);
}

// Round 4
// 5248.211 us; speedup vs baseline: 2.1483x; 1.4187x over previous
//
#include <hip/hip_runtime.h>
#include <stdint.h>

// BiLSTM (3-layer, bidirectional, 3-gate custom cell, highway) for MI355X.
//
// R12: push the R11 levers further -- the scan is trans/VALU-issue-bound.
// R11 post-mortem: prediction matched (3570->2292 us). Active-CU VALUBusy
// ~64%, MfmaUtil 28%: still activation-bound (16 trans/thread/step at
// 16 cyc wave64 quarter-rate). Changes:
//  (a) batch 4 rows/block, 16 blocks/CUs -> 2 gate-elements/thread (was 4);
//  (b) redistribution via v_permlane32_swap + v_permlane16_swap (gfx950):
//      6 cross-lane ops/gate, no LDS, no cndmask, all 64 lanes valid;
//  (c) ALL W_h in AGPRs a0..a191 (192 <= 256/wave ISA limit; unified file
//      116 arch + 192 acc = 308 regs, fine at 2 waves/SIMD since the file
//      is 2048/SIMD). w_lds deleted -> LDS reads/wave/step 20 -> 8,
//      removing the dominant SQ_LDS_BANK_CONFLICT source.
// Numerics bit-identical to R11 (same MFMA order/operands): absmax ~4.7e-3.
// Outputs fp32.

typedef unsigned short u16;
typedef unsigned int u32;
typedef unsigned long long u64;
typedef __attribute__((ext_vector_type(8))) short short8;   // 8 bf16
typedef __attribute__((ext_vector_type(4))) float f32x4;
typedef __attribute__((ext_vector_type(4))) u32 u32x4;

#define MFMA16(a, b, c) __builtin_amdgcn_mfma_f32_16x16x32_bf16((a), (b), (c), 0, 0, 0)

__device__ __forceinline__ float b2f(u16 u) {
  u32 v = ((u32)u) << 16;
  return __builtin_bit_cast(float, v);
}
__device__ __forceinline__ u16 f2b(float f) {  // round-to-nearest-even
  u32 u = __builtin_bit_cast(u32, f);
  u32 r = u + 0x7FFFu + ((u >> 16) & 1u);
  return (u16)(r >> 16);
}
__device__ __forceinline__ u16 f2h(float f) {  // fp32 -> fp16 bits
  return __builtin_bit_cast(u16, (_Float16)f);
}
__device__ __forceinline__ float h2f(u16 u) {  // fp16 bits -> fp32
  return (float)__builtin_bit_cast(_Float16, u);
}
// Overflow-proof activations: exp args always <= 0 -> no inf/NaN possible.
__device__ __forceinline__ float sigm(float x) {
  const float q = __expf(-fabsf(x));
  const float r = 1.f / (1.f + q);
  return x >= 0.f ? r : 1.f - r;
}
__device__ __forceinline__ float tanh_f(float x) {
  const float q = __expf(-2.f * fabsf(x));
  const float t = (1.f - q) / (1.f + q);
  return x >= 0.f ? t : -t;
}

// ---------------------------------------------------------------------------
// Convert x (fp32) -> bf16, vectorized float4.
// ---------------------------------------------------------------------------
__global__ void k_convert(const float* __restrict__ src, u16* __restrict__ dst, int n4) {
  int i = blockIdx.x * 256 + threadIdx.x;
  if (i < n4) {
    float4 v = ((const float4*)src)[i];
    ushort4 o;
    o.x = f2b(v.x); o.y = f2b(v.y); o.z = f2b(v.z); o.w = f2b(v.w);
    ((ushort4*)dst)[i] = o;
  }
}

// ---------------------------------------------------------------------------
// Transpose + convert all weight matrices (fp32 W[R][C] -> bf16 Wt[C][R]).
// ---------------------------------------------------------------------------
__global__ void k_transpose(const float* __restrict__ w0, const float* __restrict__ w1,
                            const float* __restrict__ w2, const float* __restrict__ w3,
                            const float* __restrict__ w4, const float* __restrict__ w5,
                            const float* __restrict__ w6, u16* __restrict__ wt) {
  int z = blockIdx.y;
  const float* src;
  int R, C;
  size_t off;
  switch (z) {
    case 0: src = w0; R = 512; C = 768; off = 0u; break;
    case 1: src = w1; R = 512; C = 768; off = 393216u; break;
    case 2: src = w2; R = 768; C = 768; off = 786432u; break;
    case 3: src = w3; R = 768; C = 768; off = 1376256u; break;
    case 4: src = w4; R = 768; C = 768; off = 1966080u; break;
    case 5: src = w5; R = 768; C = 768; off = 2555904u; break;
    default: src = w6; R = 512; C = 512; off = 3145728u; break;
  }
  size_t total = (size_t)R * C;
  size_t e = (size_t)blockIdx.x * 256 + threadIdx.x;
  if (e < total) {
    int cc = (int)(e / (size_t)R);
    int rr = (int)(e - (size_t)cc * R);
    wt[off + e] = f2b(src[(size_t)rr * C + cc]);
  }
}

// ---------------------------------------------------------------------------
// Pre-GEMM: Z[m][n] = fp16( sum_k A[m][k]*Wt[n][k] + bias[n] )  (row-major)
// A bf16 [32768][Ka]; grid=(256, 6, 2[dir]); block=256; 128x128 tile.
// EXACT R5 code (passing).
// ---------------------------------------------------------------------------
__launch_bounds__(256) __global__
void k_pregemm(const u16* __restrict__ A, int Ka,
               const u16* __restrict__ WtF, const u16* __restrict__ WtB, int Kb,
               const float* __restrict__ biasF, const float* __restrict__ biasB,
               u16* __restrict__ ZF, u16* __restrict__ ZB) {
  const int dir = blockIdx.z;
  const u16* Bt = dir ? WtB : WtF;
  const float* bias = dir ? biasB : biasF;
  u16* Z = dir ? ZB : ZF;
  const int m0 = blockIdx.x * 128;
  const int n0 = blockIdx.y * 128;

  __shared__ u16 lA[128 * 40];
  __shared__ u16 lB[128 * 40];

  const int tid = threadIdx.x;
  const int wave = tid >> 6, lane = tid & 63, quad = lane >> 4, l15 = lane & 15;
  const int wy = wave >> 1, wx = wave & 1;
  const int r = tid >> 2, kc = tid & 3;

  f32x4 acc[4][4];
#pragma unroll
  for (int i = 0; i < 4; ++i)
#pragma unroll
    for (int j = 0; j < 4; ++j)
#pragma unroll
      for (int k = 0; k < 4; ++k) acc[i][j][k] = 0.f;

  const int nk = Ka >> 5;
  for (int kk = 0; kk < nk; ++kk) {
    const u16* Ap = A + (size_t)(m0 + r) * Ka + kk * 32 + kc * 8;
    uint4 a0 = *(const uint4*)Ap;
    uint4 a1 = *(const uint4*)(Ap + (size_t)64 * Ka);
    const u16* Bp = Bt + (size_t)(n0 + r) * Kb + kk * 32 + kc * 8;
    uint4 b0 = *(const uint4*)Bp;
    uint4 b1 = *(const uint4*)(Bp + (size_t)64 * Kb);
    __syncthreads();
    *(uint4*)&lA[r * 40 + kc * 8] = a0;
    *(uint4*)&lA[(r + 64) * 40 + kc * 8] = a1;
    *(uint4*)&lB[r * 40 + kc * 8] = b0;
    *(uint4*)&lB[(r + 64) * 40 + kc * 8] = b1;
    __syncthreads();
    short8 af[4], bf[4];
#pragma unroll
    for (int mt = 0; mt < 4; ++mt)
      af[mt] = *(const short8*)&lA[(wy * 64 + mt * 16 + l15) * 40 + quad * 8];
#pragma unroll
    for (int nt = 0; nt < 4; ++nt)
      bf[nt] = *(const short8*)&lB[(wx * 64 + nt * 16 + l15) * 40 + quad * 8];
#pragma unroll
    for (int mt = 0; mt < 4; ++mt)
#pragma unroll
      for (int nt = 0; nt < 4; ++nt) acc[mt][nt] = MFMA16(af[mt], bf[nt], acc[mt][nt]);
  }

#pragma unroll
  for (int nt = 0; nt < 4; ++nt) {
    const int col = n0 + wx * 64 + nt * 16 + l15;
    const float bv = bias[col];
#pragma unroll
    for (int mt = 0; mt < 4; ++mt) {
      const int mbase = m0 + wy * 64 + mt * 16 + quad * 4;
#pragma unroll
      for (int rr = 0; rr < 4; ++rr)
        Z[(size_t)(mbase + rr) * 768 + col] = f2h(acc[mt][nt][rr] + bv);
    }
  }
}

// ---------------------------------------------------------------------------
// Highway: g = sigmoid(ys @ Wt_hw^T + b_hw); v = g*ys + (1-g)*cur.
// Dual outputs: Outb (bf16, may be null) / OutF (fp32 final, may be null).
// Cur/Outb may alias (owner-thread read-before-write); Ys never aliases.
// EXACT R5 code (passing).
// ---------------------------------------------------------------------------
__launch_bounds__(256) __global__
void k_highway(const u16* __restrict__ Ys, const u16* Cur,
               const u16* __restrict__ Wt, const float* __restrict__ bias,
               u16* Outb, float* OutF) {
  const int m0 = blockIdx.x * 128;
  const int n0 = blockIdx.y * 128;

  __shared__ u16 lA[128 * 40];
  __shared__ u16 lB[128 * 40];

  const int tid = threadIdx.x;
  const int wave = tid >> 6, lane = tid & 63, quad = lane >> 4, l15 = lane & 15;
  const int wy = wave >> 1, wx = wave & 1;
  const int r = tid >> 2, kc = tid & 3;

  f32x4 acc[4][4];
#pragma unroll
  for (int i = 0; i < 4; ++i)
#pragma unroll
    for (int j = 0; j < 4; ++j)
#pragma unroll
      for (int k = 0; k < 4; ++k) acc[i][j][k] = 0.f;

  for (int kk = 0; kk < 16; ++kk) {
    const u16* Ap = Ys + (size_t)(m0 + r) * 512 + kk * 32 + kc * 8;
    uint4 a0 = *(const uint4*)Ap;
    uint4 a1 = *(const uint4*)(Ap + (size_t)64 * 512);
    const u16* Bp = Wt + (size_t)(n0 + r) * 512 + kk * 32 + kc * 8;
    uint4 b0 = *(const uint4*)Bp;
    uint4 b1 = *(const uint4*)(Bp + (size_t)64 * 512);
    __syncthreads();
    *(uint4*)&lA[r * 40 + kc * 8] = a0;
    *(uint4*)&lA[(r + 64) * 40 + kc * 8] = a1;
    *(uint4*)&lB[r * 40 + kc * 8] = b0;
    *(uint4*)&lB[(r + 64) * 40 + kc * 8] = b1;
    __syncthreads();
    short8 af[4], bf[4];
#pragma unroll
    for (int mt = 0; mt < 4; ++mt)
      af[mt] = *(const short8*)&lA[(wy * 64 + mt * 16 + l15) * 40 + quad * 8];
#pragma unroll
    for (int nt = 0; nt < 4; ++nt)
      bf[nt] = *(const short8*)&lB[(wx * 64 + nt * 16 + l15) * 40 + quad * 8];
#pragma unroll
    for (int mt = 0; mt < 4; ++mt)
#pragma unroll
      for (int nt = 0; nt < 4; ++nt) acc[mt][nt] = MFMA16(af[mt], bf[nt], acc[mt][nt]);
  }

#pragma unroll
  for (int nt = 0; nt < 4; ++nt) {
    const int col = n0 + wx * 64 + nt * 16 + l15;
    const float bv = bias[col];
#pragma unroll
    for (int mt = 0; mt < 4; ++mt) {
      const int mbase = m0 + wy * 64 + mt * 16 + quad * 4;
#pragma unroll
      for (int rr = 0; rr < 4; ++rr) {
        const size_t idx = (size_t)(mbase + rr) * 512 + col;
        const float g = sigm(acc[mt][nt][rr] + bv);
        const float v = g * b2f(Ys[idx]) + (1.f - g) * b2f(Cur[idx]);
        if (Outb) Outb[idx] = f2b(v);
        if (OutF) OutF[idx] = v;
      }
    }
  }
}

// ---------------------------------------------------------------------------
// Scan: 16 blocks (dir = bx>>3, batch-group bg = bx&7 -> rows bg*4..bg*4+3),
// block=512 (8 waves). ALL W_h in AGPRs a0..a191 (no w_lds).
// m=16 MFMA rows 4-15 are dead; redistribution:
//   PSWAP merges nt (lanes 32-63 <- nt1), PL16 pulls rows 2,3 into odd
//   quads -> each thread owns rows {qo*2, qo*2+1} of col colc (2 elems).
// Z prefetched via asm global_load_ushort at loop top, added post-merge.
// ---------------------------------------------------------------------------

// pin one 16B weight fragment into AGPRs A0..A3
#define LP(A0, A1, A2, A3, G, NT, KK)                                              \
  do {                                                                             \
    short8 _w = *(const short8*)(Wt +                                              \
        (size_t)((G)*256 + wid * 32 + (NT)*16 + l15) * wt_pitch + koff +           \
        (KK)*32 + quad * 8);                                                       \
    u32x4 _u = __builtin_bit_cast(u32x4, _w);                                      \
    asm volatile("v_accvgpr_write_b32 a" #A0 ", %0\n\t"                            \
                 "v_accvgpr_write_b32 a" #A1 ", %1\n\t"                            \
                 "v_accvgpr_write_b32 a" #A2 ", %2\n\t"                            \
                 "v_accvgpr_write_b32 a" #A3 ", %3"                                \
                 :: "v"(_u[0]), "v"(_u[1]), "v"(_u[2]), "v"(_u[3])                 \
                 : "a" #A0, "a" #A1, "a" #A2, "a" #A3);                            \
  } while (0)

// D += A * B, B hard-coded AGPR range (accumulating form)
#define MFA(LO, HI, ACC, AF)                                                       \
  asm volatile("v_mfma_f32_16x16x32_bf16 %0, %1, a[" #LO ":" #HI "], %0"           \
               : "+v"(ACC) : "v"(AF))

// D = A * B + Z (non-accumulating first MFMA; Z = persistent zero vector)
#define MFA0(LO, HI, ACC, AF, ZZ)                                                  \
  asm volatile("v_mfma_f32_16x16x32_bf16 %0, %1, a[" #LO ":" #HI "], %2"           \
               : "=&v"(ACC) : "v"(AF), "v"(ZZ))

#define DSR(DST, ADDR, OFF)                                                        \
  asm volatile("ds_read_b128 %0, %1 offset:" #OFF : "=v"(DST) : "v"(ADDR))

#define WLG(N) asm volatile("s_waitcnt lgkmcnt(" #N ")")

// prefetch one fp16 Z element (zero-extended into a u32 VGPR)
#define GL16(DST, ADDR, OFF)                                                       \
  asm volatile("global_load_ushort %0, %1, off offset:" #OFF                       \
               : "=v"(DST) : "v"(ADDR))

// A' = {A.lanes0-31, B.lanes0-31}: swap hi(A) with lo(B)
#define PSWAP(A, B)                                                                \
  asm volatile("s_nop 1\n\tv_permlane32_swap_b32 %0, %1" : "+v"(A), "+v"(B))

// A.lanes16-31 <- B.lanes0-15; A.lanes48-63 <- B.lanes32-47
#define PL16(A, B)                                                                 \
  asm volatile("s_nop 1\n\tv_permlane16_swap_b32 %0, %1" : "+v"(A), "+v"(B))

__global__ __attribute__((amdgpu_flat_work_group_size(512, 512), amdgpu_waves_per_eu(2, 2)))
void k_scan(const u16* __restrict__ ZF, const u16* __restrict__ ZB,
            const u16* __restrict__ WtF, const u16* __restrict__ WtB,
            int wt_pitch, int koff,
            const float* __restrict__ h0, const float* __restrict__ c0,
            u16* __restrict__ ys,            // bf16 [32768][512]; fwd 0-255, bwd 256-511
            float* __restrict__ hn, float* __restrict__ cn) {  // fp32, + dir*8192
  const int tid = threadIdx.x;
  const int wid = tid >> 6, lane = tid & 63, quad = lane >> 4, l15 = lane & 15;
  const int hl = lane >> 5;        // 0: lanes 0-31 (nt0), 1: lanes 32-63 (nt1)
  const int qo = (lane >> 4) & 1;  // quad parity -> row pair (0,1) vs (2,3)
  const int dir = blockIdx.x >> 3, bg = blockIdx.x & 7;
  const u16* Z = dir ? ZB : ZF;
  const u16* Wt = dir ? WtB : WtF;

  __shared__ u16 h_lds[2][16 * 264];   // double-buffered h(t) [b][k], pitch 264

  // ---- pin ALL weight fragments into a0..a191
  // base(g,nt,kk) = ((g*2+nt)*8+kk)*4
  LP(0,1,2,3, 0,0,0);      LP(4,5,6,7, 0,0,1);      LP(8,9,10,11, 0,0,2);
  LP(12,13,14,15, 0,0,3);  LP(16,17,18,19, 0,0,4);  LP(20,21,22,23, 0,0,5);
  LP(24,25,26,27, 0,0,6);  LP(28,29,30,31, 0,0,7);
  LP(32,33,34,35, 0,1,0);  LP(36,37,38,39, 0,1,1);  LP(40,41,42,43, 0,1,2);
  LP(44,45,46,47, 0,1,3);  LP(48,49,50,51, 0,1,4);  LP(52,53,54,55, 0,1,5);
  LP(56,57,58,59, 0,1,6);  LP(60,61,62,63, 0,1,7);
  LP(64,65,66,67, 1,0,0);  LP(68,69,70,71, 1,0,1);  LP(72,73,74,75, 1,0,2);
  LP(76,77,78,79, 1,0,3);  LP(80,81,82,83, 1,0,4);  LP(84,85,86,87, 1,0,5);
  LP(88,89,90,91, 1,0,6);  LP(92,93,94,95, 1,0,7);
  LP(96,97,98,99, 1,1,0);  LP(100,101,102,103, 1,1,1); LP(104,105,106,107, 1,1,2);
  LP(108,109,110,111, 1,1,3); LP(112,113,114,115, 1,1,4); LP(116,117,118,119, 1,1,5);
  LP(120,121,122,123, 1,1,6); LP(124,125,126,127, 1,1,7);
  LP(128,129,130,131, 2,0,0); LP(132,133,134,135, 2,0,1); LP(136,137,138,139, 2,0,2);
  LP(140,141,142,143, 2,0,3); LP(144,145,146,147, 2,0,4); LP(148,149,150,151, 2,0,5);
  LP(152,153,154,155, 2,0,6); LP(156,157,158,159, 2,0,7);
  LP(160,161,162,163, 2,1,0); LP(164,165,166,167, 2,1,1); LP(168,169,170,171, 2,1,2);
  LP(172,173,174,175, 2,1,3); LP(176,177,178,179, 2,1,4); LP(180,181,182,183, 2,1,5);
  LP(184,185,186,187, 2,1,6); LP(188,189,190,191, 2,1,7);

  // ---- init h_lds: buf0 rows 0-3 = h0 broadcast; ALL other rows/bufs zero
  for (int i = tid; i < 8448; i += 512) {
    const int buf = (i >= 4224) ? 1 : 0;
    const int rem = i - buf * 4224;
    const int r = rem / 264, k = rem - r * 264;
    u16 v = (buf == 0 && r < 4 && k < 256) ? f2b(h0[k]) : (u16)0;
    ((u16*)h_lds)[i] = v;
  }
  // combined-lane column and per-thread cell state (2 rows, col-broadcast c0)
  const int colc = wid * 32 + hl * 16 + l15;
  float cst[2];
  {
    const float cv = c0[colc];
    cst[0] = cv; cst[1] = cv;
  }
  __syncthreads();

  // ---- LDS byte-address base
  const u32 hbase = (u32)(uintptr_t)&h_lds[0][0] + (u32)((l15 * 264 + quad * 8) * 2);

  // ---- running per-lane pointers (post-merge layout: row = bg*4 + qo*2 + e)
  const size_t zlane = ((size_t)bg * 4 + qo * 2) * 768 + colc;
  const u16* zp = Z + zlane + (dir ? (size_t)1023 * 24576 : (size_t)0);
  const ptrdiff_t zstep = dir ? -(ptrdiff_t)24576 : (ptrdiff_t)24576;
  const size_t yslane = ((size_t)bg * 4 + qo * 2) * 512 + (size_t)dir * 256 + colc;
  u16* ysp = ys + yslane + (dir ? (size_t)1023 * 16384 : (size_t)0);
  const ptrdiff_t ystep = dir ? -(ptrdiff_t)16384 : (ptrdiff_t)16384;

  const f32x4 zv = {0.f, 0.f, 0.f, 0.f};  // persistent MFMA SrcC zeros

  int par = 0;
#pragma unroll 1
  for (int t = 0; t < 1024; ++t) {
    // ---- prefetch Z (fp16, final layout): e=0 row, e=1 row+1; gates g
    u32 zr[3][2];
    GL16(zr[0][0], zp, 0);    GL16(zr[1][0], zp, 512);  GL16(zr[2][0], zp, 1024);
    GL16(zr[0][1], zp, 1536); GL16(zr[1][1], zp, 2048); GL16(zr[2][1], zp, 2560);

    const u32 ha = hbase + (par ? 8448u : 0u);
    short8 af0, af1;
    DSR(af0, ha, 0);
    DSR(af1, ha, 64);

    f32x4 aI[2], aJ[2], aO[2];
    // kk0 (af0): non-accumulating, SrcC = zeros
    WLG(1);
    MFA0(0,3, aI[0], af0, zv);    MFA0(32,35, aI[1], af0, zv);
    MFA0(64,67, aJ[0], af0, zv);  MFA0(96,99, aJ[1], af0, zv);
    MFA0(128,131, aO[0], af0, zv); MFA0(160,163, aO[1], af0, zv);
    DSR(af0, ha, 128);
    // kk1 (af1)
    WLG(1);
    MFA(4,7, aI[0], af1);    MFA(36,39, aI[1], af1);   MFA(68,71, aJ[0], af1);
    MFA(100,103, aJ[1], af1); MFA(132,135, aO[0], af1); MFA(164,167, aO[1], af1);
    DSR(af1, ha, 192);
    // kk2 (af0)
    WLG(1);
    MFA(8,11, aI[0], af0);   MFA(40,43, aI[1], af0);   MFA(72,75, aJ[0], af0);
    MFA(104,107, aJ[1], af0); MFA(136,139, aO[0], af0); MFA(168,171, aO[1], af0);
    DSR(af0, ha, 256);
    // kk3 (af1)
    WLG(1);
    MFA(12,15, aI[0], af1);  MFA(44,47, aI[1], af1);   MFA(76,79, aJ[0], af1);
    MFA(108,111, aJ[1], af1); MFA(140,143, aO[0], af1); MFA(172,175, aO[1], af1);
    DSR(af1, ha, 320);
    // kk4 (af0)
    WLG(1);
    MFA(16,19, aI[0], af0);  MFA(48,51, aI[1], af0);   MFA(80,83, aJ[0], af0);
    MFA(112,115, aJ[1], af0); MFA(144,147, aO[0], af0); MFA(176,179, aO[1], af0);
    DSR(af0, ha, 384);
    // kk5 (af1)
    WLG(1);
    MFA(20,23, aI[0], af1);  MFA(52,55, aI[1], af1);   MFA(84,87, aJ[0], af1);
    MFA(116,119, aJ[1], af1); MFA(148,151, aO[0], af1); MFA(180,183, aO[1], af1);
    DSR(af1, ha, 448);
    // kk6 (af0)
    WLG(1);
    MFA(24,27, aI[0], af0);  MFA(56,59, aI[1], af0);   MFA(88,91, aJ[0], af0);
    MFA(120,123, aJ[1], af0); MFA(152,155, aO[0], af0); MFA(184,187, aO[1], af0);
    // kk7 (af1)
    WLG(0);
    MFA(28,31, aI[0], af1);  MFA(60,63, aI[1], af1);   MFA(92,95, aJ[0], af1);
    MFA(124,127, aJ[1], af1); MFA(156,159, aO[0], af1); MFA(188,191, aO[1], af1);
    // fence: MFMA writes acc -> VALU reads (16 idle cycles)
    asm volatile("s_nop 7\n\ts_nop 7"
                 : "+v"(aI[0]), "+v"(aI[1]), "+v"(aJ[0]), "+v"(aJ[1]),
                   "+v"(aO[0]), "+v"(aO[1]));
    // Z prefetch must be home before the adds below
    asm volatile("s_waitcnt vmcnt(0)");
    __builtin_amdgcn_sched_barrier(0);

    // ---- redistribute: e-th value = rows {qo*2+e} of col colc
    // PSWAP merges nt into lane halves; PL16 pulls rows 2,3 into odd quads.
    float gI[2], gJ[2], gO[2];
    {
      float s0, s1, s2, s3, u0, u1, u2, u3;
      s0 = aI[0][0]; s1 = aI[0][1]; s2 = aI[0][2]; s3 = aI[0][3];
      u0 = aI[1][0]; u1 = aI[1][1]; u2 = aI[1][2]; u3 = aI[1][3];
      PSWAP(s0, u0); PSWAP(s2, u2); PL16(s0, s2);
      PSWAP(s1, u1); PSWAP(s3, u3); PL16(s1, s3);
      gI[0] = s0 + h2f((u16)zr[0][0]); gI[1] = s1 + h2f((u16)zr[0][1]);
      s0 = aJ[0][0]; s1 = aJ[0][1]; s2 = aJ[0][2]; s3 = aJ[0][3];
      u0 = aJ[1][0]; u1 = aJ[1][1]; u2 = aJ[1][2]; u3 = aJ[1][3];
      PSWAP(s0, u0); PSWAP(s2, u2); PL16(s0, s2);
      PSWAP(s1, u1); PSWAP(s3, u3); PL16(s1, s3);
      gJ[0] = s0 + h2f((u16)zr[1][0]); gJ[1] = s1 + h2f((u16)zr[1][1]);
      s0 = aO[0][0]; s1 = aO[0][1]; s2 = aO[0][2]; s3 = aO[0][3];
      u0 = aO[1][0]; u1 = aO[1][1]; u2 = aO[1][2]; u3 = aO[1][3];
      PSWAP(s0, u0); PSWAP(s2, u2); PL16(s0, s2);
      PSWAP(s1, u1); PSWAP(s3, u3); PL16(s1, s3);
      gO[0] = s0 + h2f((u16)zr[2][0]); gO[1] = s1 + h2f((u16)zr[2][1]);
    }

    // gates: i=sig, j=tanh, o=sig; c=(1-i)c + i*j; h=tanh(c)*o
    u16 hv[2];
    float hfv[2];
#pragma unroll
    for (int e = 0; e < 2; ++e) {
      const float iv = sigm(gI[e]);
      const float jv = tanh_f(gJ[e]);
      const float ov = sigm(gO[e]);
      const float c = (1.f - iv) * cst[e] + iv * jv;
      cst[e] = c;
      const float h = tanh_f(c) * ov;
      hfv[e] = h;
      hv[e] = f2b(h);
    }

    // emit ys[tt]
    ysp[0] = hv[0];
    ysp[512] = hv[1];

    if (t == 1023) {
#pragma unroll
      for (int e = 0; e < 2; ++e) {
        const int b = bg * 4 + qo * 2 + e;
        hn[dir * 8192 + b * 256 + colc] = hfv[e];
        cn[dir * 8192 + b * 256 + colc] = cst[e];
      }
      break;
    }

    // write h(t+1) rows 0-3 into the OTHER buffer; one barrier
    h_lds[par ^ 1][(qo * 2 + 0) * 264 + colc] = hv[0];
    h_lds[par ^ 1][(qo * 2 + 1) * 264 + colc] = hv[1];
    __syncthreads();
    par ^= 1;
    zp += zstep;
    ysp += ystep;
  }
}

// ---------------------------------------------------------------------------
extern "C" void kernel_launch(void* const* d_in, const int* in_sizes, int n_in,
                              void* d_out, int out_size, void* d_ws, size_t ws_size,
                              hipStream_t stream) {
  const float* x = (const float*)d_in[0];
  const float* h0 = (const float*)d_in[1];
  const float* c0 = (const float*)d_in[2];
  const float* Wf0 = (const float*)d_in[3];
  const float* bf0 = (const float*)d_in[4];
  const float* Wb0 = (const float*)d_in[5];
  const float* bb0 = (const float*)d_in[6];
  const float* Wf1 = (const float*)d_in[7];
  const float* bf1 = (const float*)d_in[8];
  const float* Wb1 = (const float*)d_in[9];
  const float* bb1 = (const float*)d_in[10];
  const float* Wf2 = (const float*)d_in[11];
  const float* bf2 = (const float*)d_in[12];
  const float* Wb2 = (const float*)d_in[13];
  const float* bb2 = (const float*)d_in[14];
  const float* Whw = (const float*)d_in[15];
  const float* bhw = (const float*)d_in[16];
  float* out = (float*)d_out;  // fp32 (reference output dtype)

  // ws layout (~182.5 MiB)
  u16* Zf = (u16*)d_ws;                // 25165824 u16 (fp16 row-major, 48 MiB)
  u16* Zb = Zf + 25165824;             // 48 MiB
  u16* bufA = Zb + 25165824;           // 16777216 bf16 (32 MiB)
  u16* bufB = bufA + 16777216;         // 16777216 bf16 (32 MiB)
  u16* xb = bufB + 16777216;           // 8388608 bf16 (16 MiB)
  u16* Wt = xb + 8388608;              // 3407872 bf16 (6.5 MiB)

  u16* Wt0f = Wt;
  u16* Wt0b = Wt0f + 393216;
  u16* Wt1f = Wt0b + 393216;
  u16* Wt1b = Wt1f + 589824;
  u16* Wt2f = Wt1b + 589824;
  u16* Wt2b = Wt2f + 589824;
  u16* Wthw = Wt2b + 589824;

  float* hnb = out + 16777216;  // h_n [6][32][256] fp32
  float* cnb = hnb + 49152;     // c_n [6][32][256] fp32

  k_convert<<<8192, 256, 0, stream>>>(x, xb, 2097152);
  k_transpose<<<dim3(2304, 7), 256, 0, stream>>>(Wf0, Wb0, Wf1, Wb1, Wf2, Wb2, Whw, Wt);

  // layer 0 (Kin=256, Wt pitch 512): ys -> bufA (no highway)
  k_pregemm<<<dim3(256, 6, 2), 256, 0, stream>>>(xb, 256, Wt0f, Wt0b, 512, bf0, bb0, Zf, Zb);
  k_scan<<<dim3(16), 512, 0, stream>>>(Zf, Zb, Wt0f, Wt0b, 512, 256, h0, c0, bufA,
                                       hnb + 0 * 8192, cnb + 0 * 8192);

  // layer 1 (Kin=512, pitch 768): ys -> bufB; highway(Ys=bufB, Cur=bufA) -> bufA (bf16)
  k_pregemm<<<dim3(256, 6, 2), 256, 0, stream>>>(bufA, 512, Wt1f, Wt1b, 768, bf1, bb1, Zf, Zb);
  k_scan<<<dim3(16), 512, 0, stream>>>(Zf, Zb, Wt1f, Wt1b, 768, 512, h0, c0, bufB,
                                       hnb + 2 * 8192, cnb + 2 * 8192);
  k_highway<<<dim3(256, 4), 256, 0, stream>>>(bufB, bufA, Wthw, bhw, bufA, (float*)nullptr);

  // layer 2: ys -> bufB; highway(Ys=bufB, Cur=bufA) -> out (fp32, final)
  k_pregemm<<<dim3(256, 6, 2), 256, 0, stream>>>(bufA, 512, Wt2f, Wt2b, 768, bf2, bb2, Zf, Zb);
  k_scan<<<dim3(16), 512, 0, stream>>>(Zf, Zb, Wt2f, Wt2b, 768, 512, h0, c0, bufB,
                                       hnb + 4 * 8192, cnb + 4 * 8192);
  k_highway<<<dim3(256, 4), 256, 0, stream>>>(bufB, bufA, Wthw, bhw, (u16*)nullptr, out);
}

// Round 6
// 4227.068 us; speedup vs baseline: 2.6673x; 1.2416x over previous
//
#include <hip/hip_runtime.h>
#include <stdint.h>

// BiLSTM (3-layer, bidirectional, 3-gate custom cell, highway) for MI355X.
//
// R14: R13's "1 h-element/thread" inside R12's proven resource envelope.
// R13 post-mortem: 1024-thr block + waves_per_eu(4,4) + 96-AGPR pin was
// unlaunchable (register files can't host 4 waves/SIMD with the pin) ->
// abort. R12 (512 thr, 2 waves/SIMD, 192 AGPR + 124 arch) is the proven
// envelope. This round keeps EXACTLY that envelope and instead halves
// rows/block: 32 blocks x 2 batch rows (dir=bx>>4, bg=bx&15). Per block:
// 2 rows x 256 h-cols = 512 h-elems = 1/thread (was 2). Wave owns strips
// A=wid*16, B=128+wid*16 x 3 gates -> same 48 frags/192 AGPR, same 48
// MFMA/wave as R12 (per-SIMD MFMA is the structural constant 96/step).
// Redistribution: 3 permlanes/gate (PL16,PL16,PSWAP; all HW-validated in
// R12): lane L -> (row=(L>>4)&1, strip=L>>5, col=l15). Trans/wave halves,
// Z loads 6->3, stores halve, 2x CUs absorb the tail.
// Outputs fp32.

typedef unsigned short u16;
typedef unsigned int u32;
typedef unsigned long long u64;
typedef __attribute__((ext_vector_type(8))) short short8;   // 8 bf16
typedef __attribute__((ext_vector_type(4))) float f32x4;
typedef __attribute__((ext_vector_type(4))) u32 u32x4;

#define MFMA16(a, b, c) __builtin_amdgcn_mfma_f32_16x16x32_bf16((a), (b), (c), 0, 0, 0)

__device__ __forceinline__ float b2f(u16 u) {
  u32 v = ((u32)u) << 16;
  return __builtin_bit_cast(float, v);
}
__device__ __forceinline__ u16 f2b(float f) {  // round-to-nearest-even
  u32 u = __builtin_bit_cast(u32, f);
  u32 r = u + 0x7FFFu + ((u >> 16) & 1u);
  return (u16)(r >> 16);
}
__device__ __forceinline__ u16 f2h(float f) {  // fp32 -> fp16 bits
  return __builtin_bit_cast(u16, (_Float16)f);
}
__device__ __forceinline__ float h2f(u16 u) {  // fp16 bits -> fp32
  return (float)__builtin_bit_cast(_Float16, u);
}
// Overflow-proof activations: exp args always <= 0 -> no inf/NaN possible.
__device__ __forceinline__ float sigm(float x) {
  const float q = __expf(-fabsf(x));
  const float r = 1.f / (1.f + q);
  return x >= 0.f ? r : 1.f - r;
}
__device__ __forceinline__ float tanh_f(float x) {
  const float q = __expf(-2.f * fabsf(x));
  const float t = (1.f - q) / (1.f + q);
  return x >= 0.f ? t : -t;
}

// ---------------------------------------------------------------------------
// Convert x (fp32) -> bf16, vectorized float4.
// ---------------------------------------------------------------------------
__global__ void k_convert(const float* __restrict__ src, u16* __restrict__ dst, int n4) {
  int i = blockIdx.x * 256 + threadIdx.x;
  if (i < n4) {
    float4 v = ((const float4*)src)[i];
    ushort4 o;
    o.x = f2b(v.x); o.y = f2b(v.y); o.z = f2b(v.z); o.w = f2b(v.w);
    ((ushort4*)dst)[i] = o;
  }
}

// ---------------------------------------------------------------------------
// Transpose + convert all weight matrices (fp32 W[R][C] -> bf16 Wt[C][R]).
// ---------------------------------------------------------------------------
__global__ void k_transpose(const float* __restrict__ w0, const float* __restrict__ w1,
                            const float* __restrict__ w2, const float* __restrict__ w3,
                            const float* __restrict__ w4, const float* __restrict__ w5,
                            const float* __restrict__ w6, u16* __restrict__ wt) {
  int z = blockIdx.y;
  const float* src;
  int R, C;
  size_t off;
  switch (z) {
    case 0: src = w0; R = 512; C = 768; off = 0u; break;
    case 1: src = w1; R = 512; C = 768; off = 393216u; break;
    case 2: src = w2; R = 768; C = 768; off = 786432u; break;
    case 3: src = w3; R = 768; C = 768; off = 1376256u; break;
    case 4: src = w4; R = 768; C = 768; off = 1966080u; break;
    case 5: src = w5; R = 768; C = 768; off = 2555904u; break;
    default: src = w6; R = 512; C = 512; off = 3145728u; break;
  }
  size_t total = (size_t)R * C;
  size_t e = (size_t)blockIdx.x * 256 + threadIdx.x;
  if (e < total) {
    int cc = (int)(e / (size_t)R);
    int rr = (int)(e - (size_t)cc * R);
    wt[off + e] = f2b(src[(size_t)rr * C + cc]);
  }
}

// ---------------------------------------------------------------------------
// Pre-GEMM: Z[m][n] = fp16( sum_k A[m][k]*Wt[n][k] + bias[n] )  (row-major)
// A bf16 [32768][Ka]; grid=(256, 6, 2[dir]); block=256; 128x128 tile.
// EXACT R5 code (passing).
// ---------------------------------------------------------------------------
__launch_bounds__(256) __global__
void k_pregemm(const u16* __restrict__ A, int Ka,
               const u16* __restrict__ WtF, const u16* __restrict__ WtB, int Kb,
               const float* __restrict__ biasF, const float* __restrict__ biasB,
               u16* __restrict__ ZF, u16* __restrict__ ZB) {
  const int dir = blockIdx.z;
  const u16* Bt = dir ? WtB : WtF;
  const float* bias = dir ? biasB : biasF;
  u16* Z = dir ? ZB : ZF;
  const int m0 = blockIdx.x * 128;
  const int n0 = blockIdx.y * 128;

  __shared__ u16 lA[128 * 40];
  __shared__ u16 lB[128 * 40];

  const int tid = threadIdx.x;
  const int wave = tid >> 6, lane = tid & 63, quad = lane >> 4, l15 = lane & 15;
  const int wy = wave >> 1, wx = wave & 1;
  const int r = tid >> 2, kc = tid & 3;

  f32x4 acc[4][4];
#pragma unroll
  for (int i = 0; i < 4; ++i)
#pragma unroll
    for (int j = 0; j < 4; ++j)
#pragma unroll
      for (int k = 0; k < 4; ++k) acc[i][j][k] = 0.f;

  const int nk = Ka >> 5;
  for (int kk = 0; kk < nk; ++kk) {
    const u16* Ap = A + (size_t)(m0 + r) * Ka + kk * 32 + kc * 8;
    uint4 a0 = *(const uint4*)Ap;
    uint4 a1 = *(const uint4*)(Ap + (size_t)64 * Ka);
    const u16* Bp = Bt + (size_t)(n0 + r) * Kb + kk * 32 + kc * 8;
    uint4 b0 = *(const uint4*)Bp;
    uint4 b1 = *(const uint4*)(Bp + (size_t)64 * Kb);
    __syncthreads();
    *(uint4*)&lA[r * 40 + kc * 8] = a0;
    *(uint4*)&lA[(r + 64) * 40 + kc * 8] = a1;
    *(uint4*)&lB[r * 40 + kc * 8] = b0;
    *(uint4*)&lB[(r + 64) * 40 + kc * 8] = b1;
    __syncthreads();
    short8 af[4], bf[4];
#pragma unroll
    for (int mt = 0; mt < 4; ++mt)
      af[mt] = *(const short8*)&lA[(wy * 64 + mt * 16 + l15) * 40 + quad * 8];
#pragma unroll
    for (int nt = 0; nt < 4; ++nt)
      bf[nt] = *(const short8*)&lB[(wx * 64 + nt * 16 + l15) * 40 + quad * 8];
#pragma unroll
    for (int mt = 0; mt < 4; ++mt)
#pragma unroll
      for (int nt = 0; nt < 4; ++nt) acc[mt][nt] = MFMA16(af[mt], bf[nt], acc[mt][nt]);
  }

#pragma unroll
  for (int nt = 0; nt < 4; ++nt) {
    const int col = n0 + wx * 64 + nt * 16 + l15;
    const float bv = bias[col];
#pragma unroll
    for (int mt = 0; mt < 4; ++mt) {
      const int mbase = m0 + wy * 64 + mt * 16 + quad * 4;
#pragma unroll
      for (int rr = 0; rr < 4; ++rr)
        Z[(size_t)(mbase + rr) * 768 + col] = f2h(acc[mt][nt][rr] + bv);
    }
  }
}

// ---------------------------------------------------------------------------
// Highway: g = sigmoid(ys @ Wt_hw^T + b_hw); v = g*ys + (1-g)*cur.
// Dual outputs: Outb (bf16, may be null) / OutF (fp32 final, may be null).
// Cur/Outb may alias (owner-thread read-before-write); Ys never aliases.
// EXACT R5 code (passing).
// ---------------------------------------------------------------------------
__launch_bounds__(256) __global__
void k_highway(const u16* __restrict__ Ys, const u16* Cur,
               const u16* __restrict__ Wt, const float* __restrict__ bias,
               u16* Outb, float* OutF) {
  const int m0 = blockIdx.x * 128;
  const int n0 = blockIdx.y * 128;

  __shared__ u16 lA[128 * 40];
  __shared__ u16 lB[128 * 40];

  const int tid = threadIdx.x;
  const int wave = tid >> 6, lane = tid & 63, quad = lane >> 4, l15 = lane & 15;
  const int wy = wave >> 1, wx = wave & 1;
  const int r = tid >> 2, kc = tid & 3;

  f32x4 acc[4][4];
#pragma unroll
  for (int i = 0; i < 4; ++i)
#pragma unroll
    for (int j = 0; j < 4; ++j)
#pragma unroll
      for (int k = 0; k < 4; ++k) acc[i][j][k] = 0.f;

  for (int kk = 0; kk < 16; ++kk) {
    const u16* Ap = Ys + (size_t)(m0 + r) * 512 + kk * 32 + kc * 8;
    uint4 a0 = *(const uint4*)Ap;
    uint4 a1 = *(const uint4*)(Ap + (size_t)64 * 512);
    const u16* Bp = Wt + (size_t)(n0 + r) * 512 + kk * 32 + kc * 8;
    uint4 b0 = *(const uint4*)Bp;
    uint4 b1 = *(const uint4*)(Bp + (size_t)64 * 512);
    __syncthreads();
    *(uint4*)&lA[r * 40 + kc * 8] = a0;
    *(uint4*)&lA[(r + 64) * 40 + kc * 8] = a1;
    *(uint4*)&lB[r * 40 + kc * 8] = b0;
    *(uint4*)&lB[(r + 64) * 40 + kc * 8] = b1;
    __syncthreads();
    short8 af[4], bf[4];
#pragma unroll
    for (int mt = 0; mt < 4; ++mt)
      af[mt] = *(const short8*)&lA[(wy * 64 + mt * 16 + l15) * 40 + quad * 8];
#pragma unroll
    for (int nt = 0; nt < 4; ++nt)
      bf[nt] = *(const short8*)&lB[(wx * 64 + nt * 16 + l15) * 40 + quad * 8];
#pragma unroll
    for (int mt = 0; mt < 4; ++mt)
#pragma unroll
      for (int nt = 0; nt < 4; ++nt) acc[mt][nt] = MFMA16(af[mt], bf[nt], acc[mt][nt]);
  }

#pragma unroll
  for (int nt = 0; nt < 4; ++nt) {
    const int col = n0 + wx * 64 + nt * 16 + l15;
    const float bv = bias[col];
#pragma unroll
    for (int mt = 0; mt < 4; ++mt) {
      const int mbase = m0 + wy * 64 + mt * 16 + quad * 4;
#pragma unroll
      for (int rr = 0; rr < 4; ++rr) {
        const size_t idx = (size_t)(mbase + rr) * 512 + col;
        const float g = sigm(acc[mt][nt][rr] + bv);
        const float v = g * b2f(Ys[idx]) + (1.f - g) * b2f(Cur[idx]);
        if (Outb) Outb[idx] = f2b(v);
        if (OutF) OutF[idx] = v;
      }
    }
  }
}

// ---------------------------------------------------------------------------
// Scan: 32 blocks (dir = bx>>4, bg = bx&15 -> rows bg*2, bg*2+1), block=512
// (8 waves, 2/SIMD -- the R12-proven envelope). Wave wid owns h-strips
// A = wid*16, B = 128+wid*16 for all 3 gates: 48 frags in AGPR a0..a191,
// 48 MFMA/wave/step (per-SIMD MFMA = structural constant 96).
// Redistribution (3 permlanes/gate): PL16(A0,A1), PL16(B0,B1), PSWAP ->
// lane L owns (row=(L>>4)&1, strip=L>>5, col=l15). 1 h-element/thread.
// ---------------------------------------------------------------------------

// pin one 16B weight fragment into AGPRs A0..A3; col n = g*256+S*128+wid*16+l15
#define LP(A0, A1, A2, A3, G, S, KK)                                               \
  do {                                                                             \
    short8 _w = *(const short8*)(Wt +                                              \
        (size_t)((G)*256 + (S)*128 + wid * 16 + l15) * wt_pitch + koff +           \
        (KK)*32 + quad * 8);                                                       \
    u32x4 _u = __builtin_bit_cast(u32x4, _w);                                      \
    asm volatile("v_accvgpr_write_b32 a" #A0 ", %0\n\t"                            \
                 "v_accvgpr_write_b32 a" #A1 ", %1\n\t"                            \
                 "v_accvgpr_write_b32 a" #A2 ", %2\n\t"                            \
                 "v_accvgpr_write_b32 a" #A3 ", %3"                                \
                 :: "v"(_u[0]), "v"(_u[1]), "v"(_u[2]), "v"(_u[3])                 \
                 : "a" #A0, "a" #A1, "a" #A2, "a" #A3);                            \
  } while (0)

// D += A * B, B hard-coded AGPR range (accumulating form)
#define MFA(LO, HI, ACC, AF)                                                       \
  asm volatile("v_mfma_f32_16x16x32_bf16 %0, %1, a[" #LO ":" #HI "], %0"           \
               : "+v"(ACC) : "v"(AF))

// D = A * B + Z (non-accumulating first MFMA; Z = persistent zero vector)
#define MFA0(LO, HI, ACC, AF, ZZ)                                                  \
  asm volatile("v_mfma_f32_16x16x32_bf16 %0, %1, a[" #LO ":" #HI "], %2"           \
               : "=&v"(ACC) : "v"(AF), "v"(ZZ))

#define DSR(DST, ADDR, OFF)                                                        \
  asm volatile("ds_read_b128 %0, %1 offset:" #OFF : "=v"(DST) : "v"(ADDR))

#define WLG(N) asm volatile("s_waitcnt lgkmcnt(" #N ")")

// prefetch one fp16 Z element (zero-extended into a u32 VGPR)
#define GL16(DST, ADDR, OFF)                                                       \
  asm volatile("global_load_ushort %0, %1, off offset:" #OFF                       \
               : "=v"(DST) : "v"(ADDR))

// A' = {A[0:31], B[0:31]}
#define PSWAP(A, B)                                                                \
  asm volatile("s_nop 1\n\tv_permlane32_swap_b32 %0, %1" : "+v"(A), "+v"(B))

// A' = {A[0:15], B[0:15], A[32:47], B[32:47]}
#define PL16(A, B)                                                                 \
  asm volatile("s_nop 1\n\tv_permlane16_swap_b32 %0, %1" : "+v"(A), "+v"(B))

__global__ __attribute__((amdgpu_flat_work_group_size(512, 512), amdgpu_waves_per_eu(2, 2)))
void k_scan(const u16* __restrict__ ZF, const u16* __restrict__ ZB,
            const u16* __restrict__ WtF, const u16* __restrict__ WtB,
            int wt_pitch, int koff,
            const float* __restrict__ h0, const float* __restrict__ c0,
            u16* __restrict__ ys,            // bf16 [32768][512]; fwd 0-255, bwd 256-511
            float* __restrict__ hn, float* __restrict__ cn) {  // fp32, + dir*8192
  const int tid = threadIdx.x;
  const int wid = tid >> 6, lane = tid & 63, quad = lane >> 4, l15 = lane & 15;
  const int qo = quad & 1;         // row within the block's 2 batch rows
  const int hs = lane >> 5;        // strip select: 0 = A (wid*16), 1 = B (128+wid*16)
  const int dir = blockIdx.x >> 4, bg = blockIdx.x & 15;
  const u16* Z = dir ? ZB : ZF;
  const u16* Wt = dir ? WtB : WtF;

  __shared__ u16 h_lds[2][16 * 264];   // double-buffered h(t) [b][k], pitch 264

  // ---- pin all 48 weight fragments into a0..a191: base(g,S,kk) = ((g*2+S)*8+kk)*4
  LP(0,1,2,3, 0,0,0);      LP(4,5,6,7, 0,0,1);      LP(8,9,10,11, 0,0,2);
  LP(12,13,14,15, 0,0,3);  LP(16,17,18,19, 0,0,4);  LP(20,21,22,23, 0,0,5);
  LP(24,25,26,27, 0,0,6);  LP(28,29,30,31, 0,0,7);
  LP(32,33,34,35, 0,1,0);  LP(36,37,38,39, 0,1,1);  LP(40,41,42,43, 0,1,2);
  LP(44,45,46,47, 0,1,3);  LP(48,49,50,51, 0,1,4);  LP(52,53,54,55, 0,1,5);
  LP(56,57,58,59, 0,1,6);  LP(60,61,62,63, 0,1,7);
  LP(64,65,66,67, 1,0,0);  LP(68,69,70,71, 1,0,1);  LP(72,73,74,75, 1,0,2);
  LP(76,77,78,79, 1,0,3);  LP(80,81,82,83, 1,0,4);  LP(84,85,86,87, 1,0,5);
  LP(88,89,90,91, 1,0,6);  LP(92,93,94,95, 1,0,7);
  LP(96,97,98,99, 1,1,0);  LP(100,101,102,103, 1,1,1); LP(104,105,106,107, 1,1,2);
  LP(108,109,110,111, 1,1,3); LP(112,113,114,115, 1,1,4); LP(116,117,118,119, 1,1,5);
  LP(120,121,122,123, 1,1,6); LP(124,125,126,127, 1,1,7);
  LP(128,129,130,131, 2,0,0); LP(132,133,134,135, 2,0,1); LP(136,137,138,139, 2,0,2);
  LP(140,141,142,143, 2,0,3); LP(144,145,146,147, 2,0,4); LP(148,149,150,151, 2,0,5);
  LP(152,153,154,155, 2,0,6); LP(156,157,158,159, 2,0,7);
  LP(160,161,162,163, 2,1,0); LP(164,165,166,167, 2,1,1); LP(168,169,170,171, 2,1,2);
  LP(172,173,174,175, 2,1,3); LP(176,177,178,179, 2,1,4); LP(180,181,182,183, 2,1,5);
  LP(184,185,186,187, 2,1,6); LP(188,189,190,191, 2,1,7);

  // ---- init h_lds: buf0 rows 0-1 = h0 broadcast; ALL other rows/bufs zero
  for (int i = tid; i < 8448; i += 512) {
    const int buf = (i >= 4224) ? 1 : 0;
    const int rem = i - buf * 4224;
    const int r = rem / 264, k = rem - r * 264;
    u16 v = (buf == 0 && r < 2 && k < 256) ? f2b(h0[k]) : (u16)0;
    ((u16*)h_lds)[i] = v;
  }
  // this thread owns (row = qo, col = colc) after redistribution
  const int colc = hs * 128 + wid * 16 + l15;
  float cst = c0[colc];
  __syncthreads();

  // ---- LDS byte-address base (A-frag: row l15, K quad*8 within kk*32)
  const u32 hbase = (u32)(uintptr_t)&h_lds[0][0] + (u32)((l15 * 264 + quad * 8) * 2);

  // ---- running per-lane pointers (post-redistribute: row = bg*2 + qo)
  const size_t zlane = ((size_t)bg * 2 + qo) * 768 + colc;
  const u16* zp = Z + zlane + (dir ? (size_t)1023 * 24576 : (size_t)0);
  const ptrdiff_t zstep = dir ? -(ptrdiff_t)24576 : (ptrdiff_t)24576;
  const size_t yslane = ((size_t)bg * 2 + qo) * 512 + (size_t)dir * 256 + colc;
  u16* ysp = ys + yslane + (dir ? (size_t)1023 * 16384 : (size_t)0);
  const ptrdiff_t ystep = dir ? -(ptrdiff_t)16384 : (ptrdiff_t)16384;

  const f32x4 zv = {0.f, 0.f, 0.f, 0.f};  // persistent MFMA SrcC zeros

  int par = 0;
#pragma unroll 1
  for (int t = 0; t < 1024; ++t) {
    // ---- prefetch Z (fp16, final layout): gates i/j/o at +0/+512B/+1024B
    u32 zr0, zr1, zr2;
    GL16(zr0, zp, 0);
    GL16(zr1, zp, 512);
    GL16(zr2, zp, 1024);

    const u32 ha = hbase + (par ? 8448u : 0u);
    short8 af0, af1;
    DSR(af0, ha, 0);
    DSR(af1, ha, 64);

    f32x4 aI[2], aJ[2], aO[2];
    // kk0 (af0): non-accumulating, SrcC = zeros
    WLG(1);
    MFA0(0,3, aI[0], af0, zv);    MFA0(32,35, aI[1], af0, zv);
    MFA0(64,67, aJ[0], af0, zv);  MFA0(96,99, aJ[1], af0, zv);
    MFA0(128,131, aO[0], af0, zv); MFA0(160,163, aO[1], af0, zv);
    DSR(af0, ha, 128);
    // kk1 (af1)
    WLG(1);
    MFA(4,7, aI[0], af1);    MFA(36,39, aI[1], af1);   MFA(68,71, aJ[0], af1);
    MFA(100,103, aJ[1], af1); MFA(132,135, aO[0], af1); MFA(164,167, aO[1], af1);
    DSR(af1, ha, 192);
    // kk2 (af0)
    WLG(1);
    MFA(8,11, aI[0], af0);   MFA(40,43, aI[1], af0);   MFA(72,75, aJ[0], af0);
    MFA(104,107, aJ[1], af0); MFA(136,139, aO[0], af0); MFA(168,171, aO[1], af0);
    DSR(af0, ha, 256);
    // kk3 (af1)
    WLG(1);
    MFA(12,15, aI[0], af1);  MFA(44,47, aI[1], af1);   MFA(76,79, aJ[0], af1);
    MFA(108,111, aJ[1], af1); MFA(140,143, aO[0], af1); MFA(172,175, aO[1], af1);
    DSR(af1, ha, 320);
    // kk4 (af0)
    WLG(1);
    MFA(16,19, aI[0], af0);  MFA(48,51, aI[1], af0);   MFA(80,83, aJ[0], af0);
    MFA(112,115, aJ[1], af0); MFA(144,147, aO[0], af0); MFA(176,179, aO[1], af0);
    DSR(af0, ha, 384);
    // kk5 (af1)
    WLG(1);
    MFA(20,23, aI[0], af1);  MFA(52,55, aI[1], af1);   MFA(84,87, aJ[0], af1);
    MFA(116,119, aJ[1], af1); MFA(148,151, aO[0], af1); MFA(180,183, aO[1], af1);
    DSR(af1, ha, 448);
    // kk6 (af0)
    WLG(1);
    MFA(24,27, aI[0], af0);  MFA(56,59, aI[1], af0);   MFA(88,91, aJ[0], af0);
    MFA(120,123, aJ[1], af0); MFA(152,155, aO[0], af0); MFA(184,187, aO[1], af0);
    // kk7 (af1)
    WLG(0);
    MFA(28,31, aI[0], af1);  MFA(60,63, aI[1], af1);   MFA(92,95, aJ[0], af1);
    MFA(124,127, aJ[1], af1); MFA(156,159, aO[0], af1); MFA(188,191, aO[1], af1);
    // fence: MFMA writes acc -> VALU reads (16 idle cycles)
    asm volatile("s_nop 7\n\ts_nop 7"
                 : "+v"(aI[0]), "+v"(aI[1]), "+v"(aJ[0]), "+v"(aJ[1]),
                   "+v"(aO[0]), "+v"(aO[1]));
    // Z prefetch must be home before the adds below
    asm volatile("s_waitcnt vmcnt(0)");
    __builtin_amdgcn_sched_barrier(0);

    // ---- redistribute: lane L <- (row (L>>4)&1, strip L>>5, col l15)
    // per gate: PL16(A0,A1) -> {r0A,r1A|..}; PL16(B0,B1) -> {r0B,r1B|..};
    // PSWAP(A,B) -> {r0A, r1A, r0B, r1B} across the 4 lane-quads.
    float gI, gJ, gO;
    {
      float a0_, a1_, b0_, b1_;
      a0_ = aI[0][0]; a1_ = aI[0][1]; b0_ = aI[1][0]; b1_ = aI[1][1];
      PL16(a0_, a1_); PL16(b0_, b1_); PSWAP(a0_, b0_);
      gI = a0_ + h2f((u16)zr0);
      a0_ = aJ[0][0]; a1_ = aJ[0][1]; b0_ = aJ[1][0]; b1_ = aJ[1][1];
      PL16(a0_, a1_); PL16(b0_, b1_); PSWAP(a0_, b0_);
      gJ = a0_ + h2f((u16)zr1);
      a0_ = aO[0][0]; a1_ = aO[0][1]; b0_ = aO[1][0]; b1_ = aO[1][1];
      PL16(a0_, a1_); PL16(b0_, b1_); PSWAP(a0_, b0_);
      gO = a0_ + h2f((u16)zr2);
    }

    // gates: i=sig, j=tanh, o=sig; c=(1-i)c + i*j; h=tanh(c)*o
    const float iv = sigm(gI);
    const float jv = tanh_f(gJ);
    const float ov = sigm(gO);
    const float c = (1.f - iv) * cst + iv * jv;
    cst = c;
    const float h = tanh_f(c) * ov;
    const u16 hv = f2b(h);

    // emit ys[tt]
    ysp[0] = hv;

    if (t == 1023) {
      const int b = bg * 2 + qo;
      hn[dir * 8192 + b * 256 + colc] = h;
      cn[dir * 8192 + b * 256 + colc] = cst;
      break;
    }

    // write h(t+1) row (=qo) into the OTHER buffer; one barrier
    h_lds[par ^ 1][qo * 264 + colc] = hv;
    __syncthreads();
    par ^= 1;
    zp += zstep;
    ysp += ystep;
  }
}

// ---------------------------------------------------------------------------
extern "C" void kernel_launch(void* const* d_in, const int* in_sizes, int n_in,
                              void* d_out, int out_size, void* d_ws, size_t ws_size,
                              hipStream_t stream) {
  const float* x = (const float*)d_in[0];
  const float* h0 = (const float*)d_in[1];
  const float* c0 = (const float*)d_in[2];
  const float* Wf0 = (const float*)d_in[3];
  const float* bf0 = (const float*)d_in[4];
  const float* Wb0 = (const float*)d_in[5];
  const float* bb0 = (const float*)d_in[6];
  const float* Wf1 = (const float*)d_in[7];
  const float* bf1 = (const float*)d_in[8];
  const float* Wb1 = (const float*)d_in[9];
  const float* bb1 = (const float*)d_in[10];
  const float* Wf2 = (const float*)d_in[11];
  const float* bf2 = (const float*)d_in[12];
  const float* Wb2 = (const float*)d_in[13];
  const float* bb2 = (const float*)d_in[14];
  const float* Whw = (const float*)d_in[15];
  const float* bhw = (const float*)d_in[16];
  float* out = (float*)d_out;  // fp32 (reference output dtype)

  // ws layout (~182.5 MiB)
  u16* Zf = (u16*)d_ws;                // 25165824 u16 (fp16 row-major, 48 MiB)
  u16* Zb = Zf + 25165824;             // 48 MiB
  u16* bufA = Zb + 25165824;           // 16777216 bf16 (32 MiB)
  u16* bufB = bufA + 16777216;         // 16777216 bf16 (32 MiB)
  u16* xb = bufB + 16777216;           // 8388608 bf16 (16 MiB)
  u16* Wt = xb + 8388608;              // 3407872 bf16 (6.5 MiB)

  u16* Wt0f = Wt;
  u16* Wt0b = Wt0f + 393216;
  u16* Wt1f = Wt0b + 393216;
  u16* Wt1b = Wt1f + 589824;
  u16* Wt2f = Wt1b + 589824;
  u16* Wt2b = Wt2f + 589824;
  u16* Wthw = Wt2b + 589824;

  float* hnb = out + 16777216;  // h_n [6][32][256] fp32
  float* cnb = hnb + 49152;     // c_n [6][32][256] fp32

  k_convert<<<8192, 256, 0, stream>>>(x, xb, 2097152);
  k_transpose<<<dim3(2304, 7), 256, 0, stream>>>(Wf0, Wb0, Wf1, Wb1, Wf2, Wb2, Whw, Wt);

  // layer 0 (Kin=256, Wt pitch 512): ys -> bufA (no highway)
  k_pregemm<<<dim3(256, 6, 2), 256, 0, stream>>>(xb, 256, Wt0f, Wt0b, 512, bf0, bb0, Zf, Zb);
  k_scan<<<dim3(32), 512, 0, stream>>>(Zf, Zb, Wt0f, Wt0b, 512, 256, h0, c0, bufA,
                                       hnb + 0 * 8192, cnb + 0 * 8192);

  // layer 1 (Kin=512, pitch 768): ys -> bufB; highway(Ys=bufB, Cur=bufA) -> bufA (bf16)
  k_pregemm<<<dim3(256, 6, 2), 256, 0, stream>>>(bufA, 512, Wt1f, Wt1b, 768, bf1, bb1, Zf, Zb);
  k_scan<<<dim3(32), 512, 0, stream>>>(Zf, Zb, Wt1f, Wt1b, 768, 512, h0, c0, bufB,
                                       hnb + 2 * 8192, cnb + 2 * 8192);
  k_highway<<<dim3(256, 4), 256, 0, stream>>>(bufB, bufA, Wthw, bhw, bufA, (float*)nullptr);

  // layer 2: ys -> bufB; highway(Ys=bufB, Cur=bufA) -> out (fp32, final)
  k_pregemm<<<dim3(256, 6, 2), 256, 0, stream>>>(bufA, 512, Wt2f, Wt2b, 768, bf2, bb2, Zf, Zb);
  k_scan<<<dim3(32), 512, 0, stream>>>(Zf, Zb, Wt2f, Wt2b, 768, 512, h0, c0, bufB,
                                       hnb + 4 * 8192, cnb + 4 * 8192);
  k_highway<<<dim3(256, 4), 256, 0, stream>>>(bufB, bufA, Wthw, bhw, (u16*)nullptr, out);
}

// Round 12
// 4141.450 us; speedup vs baseline: 2.7224x; 1.0207x over previous
//
#include <hip/hip_runtime.h>
#include <stdint.h>

// BiLSTM (3-layer, bidirectional, 3-gate custom cell, highway) for MI355X.
//
// R17: fix R16's NaN -- the Z prefetch-ahead made zr0..2 LOOP-CARRIED
// registers defined by asm-volatile loads. The compiler can't see asm defs
// as loads (rule #18 hazard class): the backedge phi for zr0..2 is resolved
// with v_mov copies that can execute while the global_load is in flight ->
// garbage fp16 -> NaN -> poisons the loop-carried cell state. R14 was safe
// (def+use within one iteration, no phi). Fix: COMPILER-VISIBLE plain u16
// loads for Z -- the compiler inserts precise vmcnt before every use (incl.
// copies) and handles the phi. Loads issued before the ys store => the
// pre-use wait leaves the store ack outstanding (vmcnt retires in issue
// order), so (a) lgkm-only barrier keeps its benefit. Manual vmcnt(0)+
// sched_barrier pair deleted. R14's MFMA schedule/fences kept verbatim.
// Numerics identical to R12/R14 -> absmax 4.684e-3. Outputs fp32.

typedef unsigned short u16;
typedef unsigned int u32;
typedef unsigned long long u64;
typedef __attribute__((ext_vector_type(8))) short short8;   // 8 bf16
typedef __attribute__((ext_vector_type(4))) float f32x4;
typedef __attribute__((ext_vector_type(4))) u32 u32x4;

#define MFMA16(a, b, c) __builtin_amdgcn_mfma_f32_16x16x32_bf16((a), (b), (c), 0, 0, 0)

__device__ __forceinline__ float b2f(u16 u) {
  u32 v = ((u32)u) << 16;
  return __builtin_bit_cast(float, v);
}
__device__ __forceinline__ u16 f2b(float f) {  // round-to-nearest-even
  u32 u = __builtin_bit_cast(u32, f);
  u32 r = u + 0x7FFFu + ((u >> 16) & 1u);
  return (u16)(r >> 16);
}
__device__ __forceinline__ u16 f2h(float f) {  // fp32 -> fp16 bits
  return __builtin_bit_cast(u16, (_Float16)f);
}
__device__ __forceinline__ float h2f(u16 u) {  // fp16 bits -> fp32
  return (float)__builtin_bit_cast(_Float16, u);
}
// Overflow-proof activations: exp args always <= 0 -> no inf/NaN possible.
__device__ __forceinline__ float sigm(float x) {
  const float q = __expf(-fabsf(x));
  const float r = 1.f / (1.f + q);
  return x >= 0.f ? r : 1.f - r;
}
__device__ __forceinline__ float tanh_f(float x) {
  const float q = __expf(-2.f * fabsf(x));
  const float t = (1.f - q) / (1.f + q);
  return x >= 0.f ? t : -t;
}

// ---------------------------------------------------------------------------
// Convert x (fp32) -> bf16, vectorized float4.
// ---------------------------------------------------------------------------
__global__ void k_convert(const float* __restrict__ src, u16* __restrict__ dst, int n4) {
  int i = blockIdx.x * 256 + threadIdx.x;
  if (i < n4) {
    float4 v = ((const float4*)src)[i];
    ushort4 o;
    o.x = f2b(v.x); o.y = f2b(v.y); o.z = f2b(v.z); o.w = f2b(v.w);
    ((ushort4*)dst)[i] = o;
  }
}

// ---------------------------------------------------------------------------
// Transpose + convert all weight matrices (fp32 W[R][C] -> bf16 Wt[C][R]).
// ---------------------------------------------------------------------------
__global__ void k_transpose(const float* __restrict__ w0, const float* __restrict__ w1,
                            const float* __restrict__ w2, const float* __restrict__ w3,
                            const float* __restrict__ w4, const float* __restrict__ w5,
                            const float* __restrict__ w6, u16* __restrict__ wt) {
  int z = blockIdx.y;
  const float* src;
  int R, C;
  size_t off;
  switch (z) {
    case 0: src = w0; R = 512; C = 768; off = 0u; break;
    case 1: src = w1; R = 512; C = 768; off = 393216u; break;
    case 2: src = w2; R = 768; C = 768; off = 786432u; break;
    case 3: src = w3; R = 768; C = 768; off = 1376256u; break;
    case 4: src = w4; R = 768; C = 768; off = 1966080u; break;
    case 5: src = w5; R = 768; C = 768; off = 2555904u; break;
    default: src = w6; R = 512; C = 512; off = 3145728u; break;
  }
  size_t total = (size_t)R * C;
  size_t e = (size_t)blockIdx.x * 256 + threadIdx.x;
  if (e < total) {
    int cc = (int)(e / (size_t)R);
    int rr = (int)(e - (size_t)cc * R);
    wt[off + e] = f2b(src[(size_t)rr * C + cc]);
  }
}

// ---------------------------------------------------------------------------
// Pre-GEMM: Z[m][n] = fp16( sum_k A[m][k]*Wt[n][k] + bias[n] )  (row-major)
// A bf16 [32768][Ka]; grid=(256, 6, 2[dir]); block=256; 128x128 tile.
// EXACT R5 code (passing).
// ---------------------------------------------------------------------------
__launch_bounds__(256) __global__
void k_pregemm(const u16* __restrict__ A, int Ka,
               const u16* __restrict__ WtF, const u16* __restrict__ WtB, int Kb,
               const float* __restrict__ biasF, const float* __restrict__ biasB,
               u16* __restrict__ ZF, u16* __restrict__ ZB) {
  const int dir = blockIdx.z;
  const u16* Bt = dir ? WtB : WtF;
  const float* bias = dir ? biasB : biasF;
  u16* Z = dir ? ZB : ZF;
  const int m0 = blockIdx.x * 128;
  const int n0 = blockIdx.y * 128;

  __shared__ u16 lA[128 * 40];
  __shared__ u16 lB[128 * 40];

  const int tid = threadIdx.x;
  const int wave = tid >> 6, lane = tid & 63, quad = lane >> 4, l15 = lane & 15;
  const int wy = wave >> 1, wx = wave & 1;
  const int r = tid >> 2, kc = tid & 3;

  f32x4 acc[4][4];
#pragma unroll
  for (int i = 0; i < 4; ++i)
#pragma unroll
    for (int j = 0; j < 4; ++j)
#pragma unroll
      for (int k = 0; k < 4; ++k) acc[i][j][k] = 0.f;

  const int nk = Ka >> 5;
  for (int kk = 0; kk < nk; ++kk) {
    const u16* Ap = A + (size_t)(m0 + r) * Ka + kk * 32 + kc * 8;
    uint4 a0 = *(const uint4*)Ap;
    uint4 a1 = *(const uint4*)(Ap + (size_t)64 * Ka);
    const u16* Bp = Bt + (size_t)(n0 + r) * Kb + kk * 32 + kc * 8;
    uint4 b0 = *(const uint4*)Bp;
    uint4 b1 = *(const uint4*)(Bp + (size_t)64 * Kb);
    __syncthreads();
    *(uint4*)&lA[r * 40 + kc * 8] = a0;
    *(uint4*)&lA[(r + 64) * 40 + kc * 8] = a1;
    *(uint4*)&lB[r * 40 + kc * 8] = b0;
    *(uint4*)&lB[(r + 64) * 40 + kc * 8] = b1;
    __syncthreads();
    short8 af[4], bf[4];
#pragma unroll
    for (int mt = 0; mt < 4; ++mt)
      af[mt] = *(const short8*)&lA[(wy * 64 + mt * 16 + l15) * 40 + quad * 8];
#pragma unroll
    for (int nt = 0; nt < 4; ++nt)
      bf[nt] = *(const short8*)&lB[(wx * 64 + nt * 16 + l15) * 40 + quad * 8];
#pragma unroll
    for (int mt = 0; mt < 4; ++mt)
#pragma unroll
      for (int nt = 0; nt < 4; ++nt) acc[mt][nt] = MFMA16(af[mt], bf[nt], acc[mt][nt]);
  }

#pragma unroll
  for (int nt = 0; nt < 4; ++nt) {
    const int col = n0 + wx * 64 + nt * 16 + l15;
    const float bv = bias[col];
#pragma unroll
    for (int mt = 0; mt < 4; ++mt) {
      const int mbase = m0 + wy * 64 + mt * 16 + quad * 4;
#pragma unroll
      for (int rr = 0; rr < 4; ++rr)
        Z[(size_t)(mbase + rr) * 768 + col] = f2h(acc[mt][nt][rr] + bv);
    }
  }
}

// ---------------------------------------------------------------------------
// Highway: g = sigmoid(ys @ Wt_hw^T + b_hw); v = g*ys + (1-g)*cur.
// Dual outputs: Outb (bf16, may be null) / OutF (fp32 final, may be null).
// Cur/Outb may alias (owner-thread read-before-write); Ys never aliases.
// EXACT R5 code (passing).
// ---------------------------------------------------------------------------
__launch_bounds__(256) __global__
void k_highway(const u16* __restrict__ Ys, const u16* Cur,
               const u16* __restrict__ Wt, const float* __restrict__ bias,
               u16* Outb, float* OutF) {
  const int m0 = blockIdx.x * 128;
  const int n0 = blockIdx.y * 128;

  __shared__ u16 lA[128 * 40];
  __shared__ u16 lB[128 * 40];

  const int tid = threadIdx.x;
  const int wave = tid >> 6, lane = tid & 63, quad = lane >> 4, l15 = lane & 15;
  const int wy = wave >> 1, wx = wave & 1;
  const int r = tid >> 2, kc = tid & 3;

  f32x4 acc[4][4];
#pragma unroll
  for (int i = 0; i < 4; ++i)
#pragma unroll
    for (int j = 0; j < 4; ++j)
#pragma unroll
      for (int k = 0; k < 4; ++k) acc[i][j][k] = 0.f;

  for (int kk = 0; kk < 16; ++kk) {
    const u16* Ap = Ys + (size_t)(m0 + r) * 512 + kk * 32 + kc * 8;
    uint4 a0 = *(const uint4*)Ap;
    uint4 a1 = *(const uint4*)(Ap + (size_t)64 * 512);
    const u16* Bp = Wt + (size_t)(n0 + r) * 512 + kk * 32 + kc * 8;
    uint4 b0 = *(const uint4*)Bp;
    uint4 b1 = *(const uint4*)(Bp + (size_t)64 * 512);
    __syncthreads();
    *(uint4*)&lA[r * 40 + kc * 8] = a0;
    *(uint4*)&lA[(r + 64) * 40 + kc * 8] = a1;
    *(uint4*)&lB[r * 40 + kc * 8] = b0;
    *(uint4*)&lB[(r + 64) * 40 + kc * 8] = b1;
    __syncthreads();
    short8 af[4], bf[4];
#pragma unroll
    for (int mt = 0; mt < 4; ++mt)
      af[mt] = *(const short8*)&lA[(wy * 64 + mt * 16 + l15) * 40 + quad * 8];
#pragma unroll
    for (int nt = 0; nt < 4; ++nt)
      bf[nt] = *(const short8*)&lB[(wx * 64 + nt * 16 + l15) * 40 + quad * 8];
#pragma unroll
    for (int mt = 0; mt < 4; ++mt)
#pragma unroll
      for (int nt = 0; nt < 4; ++nt) acc[mt][nt] = MFMA16(af[mt], bf[nt], acc[mt][nt]);
  }

#pragma unroll
  for (int nt = 0; nt < 4; ++nt) {
    const int col = n0 + wx * 64 + nt * 16 + l15;
    const float bv = bias[col];
#pragma unroll
    for (int mt = 0; mt < 4; ++mt) {
      const int mbase = m0 + wy * 64 + mt * 16 + quad * 4;
#pragma unroll
      for (int rr = 0; rr < 4; ++rr) {
        const size_t idx = (size_t)(mbase + rr) * 512 + col;
        const float g = sigm(acc[mt][nt][rr] + bv);
        const float v = g * b2f(Ys[idx]) + (1.f - g) * b2f(Cur[idx]);
        if (Outb) Outb[idx] = f2b(v);
        if (OutF) OutF[idx] = v;
      }
    }
  }
}

// ---------------------------------------------------------------------------
// Scan: 32 blocks (dir = bx>>4, bg = bx&15 -> rows bg*2, bg*2+1), block=512
// (8 waves, 2/SIMD -- the R12/R14-proven envelope). Wave wid owns h-strips
// A = wid*16, B = 128+wid*16 for all 3 gates: 48 frags in AGPR a0..a191,
// 48 MFMA/wave/step. R14 schedule kept verbatim. Deltas from R14:
//  (a) lgkm-only barrier (no per-step vmcnt drain of the ys store ack);
//  (b) Z prefetched one step ahead via COMPILER-VISIBLE u16 loads
//      (loop-carried locals; compiler inserts precise vmcnt before uses).
// ---------------------------------------------------------------------------

// pin one 16B weight fragment into AGPRs A0..A3; col n = g*256+S*128+wid*16+l15
#define LP(A0, A1, A2, A3, G, S, KK)                                               \
  do {                                                                             \
    short8 _w = *(const short8*)(Wt +                                              \
        (size_t)((G)*256 + (S)*128 + wid * 16 + l15) * wt_pitch + koff +           \
        (KK)*32 + quad * 8);                                                       \
    u32x4 _u = __builtin_bit_cast(u32x4, _w);                                      \
    asm volatile("v_accvgpr_write_b32 a" #A0 ", %0\n\t"                            \
                 "v_accvgpr_write_b32 a" #A1 ", %1\n\t"                            \
                 "v_accvgpr_write_b32 a" #A2 ", %2\n\t"                            \
                 "v_accvgpr_write_b32 a" #A3 ", %3"                                \
                 :: "v"(_u[0]), "v"(_u[1]), "v"(_u[2]), "v"(_u[3])                 \
                 : "a" #A0, "a" #A1, "a" #A2, "a" #A3);                            \
  } while (0)

// D += A * B, B hard-coded AGPR range (accumulating form)
#define MFA(LO, HI, ACC, AF)                                                       \
  asm volatile("v_mfma_f32_16x16x32_bf16 %0, %1, a[" #LO ":" #HI "], %0"           \
               : "+v"(ACC) : "v"(AF))

// D = A * B + Z (non-accumulating first MFMA; Z = persistent zero vector)
#define MFA0(LO, HI, ACC, AF, ZZ)                                                  \
  asm volatile("v_mfma_f32_16x16x32_bf16 %0, %1, a[" #LO ":" #HI "], %2"           \
               : "=&v"(ACC) : "v"(AF), "v"(ZZ))

#define DSR(DST, ADDR, OFF)                                                        \
  asm volatile("ds_read_b128 %0, %1 offset:" #OFF : "=v"(DST) : "v"(ADDR))

#define WLG(N) asm volatile("s_waitcnt lgkmcnt(" #N ")")

// A' = {A[0:31], B[0:31]}
#define PSWAP(A, B)                                                                \
  asm volatile("s_nop 1\n\tv_permlane32_swap_b32 %0, %1" : "+v"(A), "+v"(B))

// A' = {A[0:15], B[0:15], A[32:47], B[32:47]}
#define PL16(A, B)                                                                 \
  asm volatile("s_nop 1\n\tv_permlane16_swap_b32 %0, %1" : "+v"(A), "+v"(B))

__global__ __attribute__((amdgpu_flat_work_group_size(512, 512), amdgpu_waves_per_eu(2, 2)))
void k_scan(const u16* __restrict__ ZF, const u16* __restrict__ ZB,
            const u16* __restrict__ WtF, const u16* __restrict__ WtB,
            int wt_pitch, int koff,
            const float* __restrict__ h0, const float* __restrict__ c0,
            u16* __restrict__ ys,            // bf16 [32768][512]; fwd 0-255, bwd 256-511
            float* __restrict__ hn, float* __restrict__ cn) {  // fp32, + dir*8192
  const int tid = threadIdx.x;
  const int wid = tid >> 6, lane = tid & 63, quad = lane >> 4, l15 = lane & 15;
  const int qo = quad & 1;         // row within the block's 2 batch rows
  const int hs = lane >> 5;        // strip select: 0 = A (wid*16), 1 = B (128+wid*16)
  const int dir = blockIdx.x >> 4, bg = blockIdx.x & 15;
  const u16* Z = dir ? ZB : ZF;
  const u16* Wt = dir ? WtB : WtF;

  __shared__ u16 h_lds[2][16 * 264];   // double-buffered h(t) [b][k], pitch 264

  // ---- pin all 48 weight fragments into a0..a191: base(g,S,kk) = ((g*2+S)*8+kk)*4
  LP(0,1,2,3, 0,0,0);      LP(4,5,6,7, 0,0,1);      LP(8,9,10,11, 0,0,2);
  LP(12,13,14,15, 0,0,3);  LP(16,17,18,19, 0,0,4);  LP(20,21,22,23, 0,0,5);
  LP(24,25,26,27, 0,0,6);  LP(28,29,30,31, 0,0,7);
  LP(32,33,34,35, 0,1,0);  LP(36,37,38,39, 0,1,1);  LP(40,41,42,43, 0,1,2);
  LP(44,45,46,47, 0,1,3);  LP(48,49,50,51, 0,1,4);  LP(52,53,54,55, 0,1,5);
  LP(56,57,58,59, 0,1,6);  LP(60,61,62,63, 0,1,7);
  LP(64,65,66,67, 1,0,0);  LP(68,69,70,71, 1,0,1);  LP(72,73,74,75, 1,0,2);
  LP(76,77,78,79, 1,0,3);  LP(80,81,82,83, 1,0,4);  LP(84,85,86,87, 1,0,5);
  LP(88,89,90,91, 1,0,6);  LP(92,93,94,95, 1,0,7);
  LP(96,97,98,99, 1,1,0);  LP(100,101,102,103, 1,1,1); LP(104,105,106,107, 1,1,2);
  LP(108,109,110,111, 1,1,3); LP(112,113,114,115, 1,1,4); LP(116,117,118,119, 1,1,5);
  LP(120,121,122,123, 1,1,6); LP(124,125,126,127, 1,1,7);
  LP(128,129,130,131, 2,0,0); LP(132,133,134,135, 2,0,1); LP(136,137,138,139, 2,0,2);
  LP(140,141,142,143, 2,0,3); LP(144,145,146,147, 2,0,4); LP(148,149,150,151, 2,0,5);
  LP(152,153,154,155, 2,0,6); LP(156,157,158,159, 2,0,7);
  LP(160,161,162,163, 2,1,0); LP(164,165,166,167, 2,1,1); LP(168,169,170,171, 2,1,2);
  LP(172,173,174,175, 2,1,3); LP(176,177,178,179, 2,1,4); LP(180,181,182,183, 2,1,5);
  LP(184,185,186,187, 2,1,6); LP(188,189,190,191, 2,1,7);

  // ---- init h_lds: buf0 rows 0-1 = h0 broadcast; ALL other rows/bufs zero
  for (int i = tid; i < 8448; i += 512) {
    const int buf = (i >= 4224) ? 1 : 0;
    const int rem = i - buf * 4224;
    const int r = rem / 264, k = rem - r * 264;
    u16 v = (buf == 0 && r < 2 && k < 256) ? f2b(h0[k]) : (u16)0;
    ((u16*)h_lds)[i] = v;
  }
  // this thread owns (row = qo, col = colc) after redistribution
  const int colc = hs * 128 + wid * 16 + l15;
  float cst = c0[colc];
  __syncthreads();

  // ---- LDS byte-address base (A-frag: row l15, K quad*8 within kk*32)
  const u32 hbase = (u32)(uintptr_t)&h_lds[0][0] + (u32)((l15 * 264 + quad * 8) * 2);

  // ---- running per-lane pointers (post-redistribute: row = bg*2 + qo)
  const size_t zlane = ((size_t)bg * 2 + qo) * 768 + colc;
  const u16* zp = Z + zlane + (dir ? (size_t)1023 * 24576 : (size_t)0);
  const ptrdiff_t zstep = dir ? -(ptrdiff_t)24576 : (ptrdiff_t)24576;
  const size_t yslane = ((size_t)bg * 2 + qo) * 512 + (size_t)dir * 256 + colc;
  u16* ysp = ys + yslane + (dir ? (size_t)1023 * 16384 : (size_t)0);
  const ptrdiff_t ystep = dir ? -(ptrdiff_t)16384 : (ptrdiff_t)16384;

  const f32x4 zv = {0.f, 0.f, 0.f, 0.f};  // persistent MFMA SrcC zeros

  // ---- prologue: Z loads for t=0 (compiler-visible; consumed post-MFMA)
  u16 zc0 = zp[0], zc1 = zp[256], zc2 = zp[512];

  int par = 0;
#pragma unroll 1
  for (int t = 0; t < 1024; ++t) {
    const u32 ha = hbase + (par ? 8448u : 0u);
    short8 af0, af1;
    DSR(af0, ha, 0);
    DSR(af1, ha, 64);

    f32x4 aI[2], aJ[2], aO[2];
    // kk0 (af0): non-accumulating, SrcC = zeros
    WLG(1);
    MFA0(0,3, aI[0], af0, zv);    MFA0(32,35, aI[1], af0, zv);
    MFA0(64,67, aJ[0], af0, zv);  MFA0(96,99, aJ[1], af0, zv);
    MFA0(128,131, aO[0], af0, zv); MFA0(160,163, aO[1], af0, zv);
    DSR(af0, ha, 128);
    // kk1 (af1)
    WLG(1);
    MFA(4,7, aI[0], af1);    MFA(36,39, aI[1], af1);   MFA(68,71, aJ[0], af1);
    MFA(100,103, aJ[1], af1); MFA(132,135, aO[0], af1); MFA(164,167, aO[1], af1);
    DSR(af1, ha, 192);
    // kk2 (af0)
    WLG(1);
    MFA(8,11, aI[0], af0);   MFA(40,43, aI[1], af0);   MFA(72,75, aJ[0], af0);
    MFA(104,107, aJ[1], af0); MFA(136,139, aO[0], af0); MFA(168,171, aO[1], af0);
    DSR(af0, ha, 256);
    // kk3 (af1)
    WLG(1);
    MFA(12,15, aI[0], af1);  MFA(44,47, aI[1], af1);   MFA(76,79, aJ[0], af1);
    MFA(108,111, aJ[1], af1); MFA(140,143, aO[0], af1); MFA(172,175, aO[1], af1);
    DSR(af1, ha, 320);
    // kk4 (af0)
    WLG(1);
    MFA(16,19, aI[0], af0);  MFA(48,51, aI[1], af0);   MFA(80,83, aJ[0], af0);
    MFA(112,115, aJ[1], af0); MFA(144,147, aO[0], af0); MFA(176,179, aO[1], af0);
    DSR(af0, ha, 384);
    // kk5 (af1)
    WLG(1);
    MFA(20,23, aI[0], af1);  MFA(52,55, aI[1], af1);   MFA(84,87, aJ[0], af1);
    MFA(116,119, aJ[1], af1); MFA(148,151, aO[0], af1); MFA(180,183, aO[1], af1);
    DSR(af1, ha, 448);
    // kk6 (af0)
    WLG(1);
    MFA(24,27, aI[0], af0);  MFA(56,59, aI[1], af0);   MFA(88,91, aJ[0], af0);
    MFA(120,123, aJ[1], af0); MFA(152,155, aO[0], af0); MFA(184,187, aO[1], af0);
    // kk7 (af1)
    WLG(0);
    MFA(28,31, aI[0], af1);  MFA(60,63, aI[1], af1);   MFA(92,95, aJ[0], af1);
    MFA(124,127, aJ[1], af1); MFA(156,159, aO[0], af1); MFA(188,191, aO[1], af1);
    // fence: MFMA writes acc -> VALU reads (16 idle cycles)
    asm volatile("s_nop 7\n\ts_nop 7"
                 : "+v"(aI[0]), "+v"(aI[1]), "+v"(aJ[0]), "+v"(aJ[1]),
                   "+v"(aO[0]), "+v"(aO[1]));

    // ---- redistribute: lane L <- (row (L>>4)&1, strip L>>5, col l15)
    // Z values zc0..2 were loaded one step ago (compiler inserts the
    // precise vmcnt wait here -- loads are older than the ys store, so
    // the store ack stays outstanding).
    float gI, gJ, gO;
    {
      float a0_, a1_, b0_, b1_;
      a0_ = aI[0][0]; a1_ = aI[0][1]; b0_ = aI[1][0]; b1_ = aI[1][1];
      PL16(a0_, a1_); PL16(b0_, b1_); PSWAP(a0_, b0_);
      gI = a0_ + h2f(zc0);
      a0_ = aJ[0][0]; a1_ = aJ[0][1]; b0_ = aJ[1][0]; b1_ = aJ[1][1];
      PL16(a0_, a1_); PL16(b0_, b1_); PSWAP(a0_, b0_);
      gJ = a0_ + h2f(zc1);
      a0_ = aO[0][0]; a1_ = aO[0][1]; b0_ = aO[1][0]; b1_ = aO[1][1];
      PL16(a0_, a1_); PL16(b0_, b1_); PSWAP(a0_, b0_);
      gO = a0_ + h2f(zc2);
    }

    // ---- prefetch Z for t+1 (compiler-visible loads, issued before the
    // ys store so the pre-use wait next iteration skips the store ack)
    if (t < 1023) {
      zp += zstep;
      zc0 = zp[0];
      zc1 = zp[256];
      zc2 = zp[512];
    }

    // gates: i=sig, j=tanh, o=sig; c=(1-i)c + i*j; h=tanh(c)*o
    const float iv = sigm(gI);
    const float jv = tanh_f(gJ);
    const float ov = sigm(gO);
    const float c = (1.f - iv) * cst + iv * jv;
    cst = c;
    const float h = tanh_f(c) * ov;
    const u16 hv = f2b(h);

    // emit ys[tt]
    ysp[0] = hv;

    if (t == 1023) {
      const int b = bg * 2 + qo;
      hn[dir * 8192 + b * 256 + colc] = h;
      cn[dir * 8192 + b * 256 + colc] = cst;
      break;
    }

    // write h(t+1) row (=qo) into the OTHER buffer; lgkm-only barrier
    // (do NOT drain vmcnt: the ys store needs no ordering inside the loop)
    h_lds[par ^ 1][qo * 264 + colc] = hv;
    asm volatile("s_waitcnt lgkmcnt(0)" ::: "memory");
    __builtin_amdgcn_s_barrier();
    par ^= 1;
    ysp += ystep;
  }
}

// ---------------------------------------------------------------------------
extern "C" void kernel_launch(void* const* d_in, const int* in_sizes, int n_in,
                              void* d_out, int out_size, void* d_ws, size_t ws_size,
                              hipStream_t stream) {
  const float* x = (const float*)d_in[0];
  const float* h0 = (const float*)d_in[1];
  const float* c0 = (const float*)d_in[2];
  const float* Wf0 = (const float*)d_in[3];
  const float* bf0 = (const float*)d_in[4];
  const float* Wb0 = (const float*)d_in[5];
  const float* bb0 = (const float*)d_in[6];
  const float* Wf1 = (const float*)d_in[7];
  const float* bf1 = (const float*)d_in[8];
  const float* Wb1 = (const float*)d_in[9];
  const float* bb1 = (const float*)d_in[10];
  const float* Wf2 = (const float*)d_in[11];
  const float* bf2 = (const float*)d_in[12];
  const float* Wb2 = (const float*)d_in[13];
  const float* bb2 = (const float*)d_in[14];
  const float* Whw = (const float*)d_in[15];
  const float* bhw = (const float*)d_in[16];
  float* out = (float*)d_out;  // fp32 (reference output dtype)

  // ws layout (~182.5 MiB)
  u16* Zf = (u16*)d_ws;                // 25165824 u16 (fp16 row-major, 48 MiB)
  u16* Zb = Zf + 25165824;             // 48 MiB
  u16* bufA = Zb + 25165824;           // 16777216 bf16 (32 MiB)
  u16* bufB = bufA + 16777216;         // 16777216 bf16 (32 MiB)
  u16* xb = bufB + 16777216;           // 8388608 bf16 (16 MiB)
  u16* Wt = xb + 8388608;              // 3407872 bf16 (6.5 MiB)

  u16* Wt0f = Wt;
  u16* Wt0b = Wt0f + 393216;
  u16* Wt1f = Wt0b + 393216;
  u16* Wt1b = Wt1f + 589824;
  u16* Wt2f = Wt1b + 589824;
  u16* Wt2b = Wt2f + 589824;
  u16* Wthw = Wt2b + 589824;

  float* hnb = out + 16777216;  // h_n [6][32][256] fp32
  float* cnb = hnb + 49152;     // c_n [6][32][256] fp32

  k_convert<<<8192, 256, 0, stream>>>(x, xb, 2097152);
  k_transpose<<<dim3(2304, 7), 256, 0, stream>>>(Wf0, Wb0, Wf1, Wb1, Wf2, Wb2, Whw, Wt);

  // layer 0 (Kin=256, Wt pitch 512): ys -> bufA (no highway)
  k_pregemm<<<dim3(256, 6, 2), 256, 0, stream>>>(xb, 256, Wt0f, Wt0b, 512, bf0, bb0, Zf, Zb);
  k_scan<<<dim3(32), 512, 0, stream>>>(Zf, Zb, Wt0f, Wt0b, 512, 256, h0, c0, bufA,
                                       hnb + 0 * 8192, cnb + 0 * 8192);

  // layer 1 (Kin=512, pitch 768): ys -> bufB; highway(Ys=bufB, Cur=bufA) -> bufA (bf16)
  k_pregemm<<<dim3(256, 6, 2), 256, 0, stream>>>(bufA, 512, Wt1f, Wt1b, 768, bf1, bb1, Zf, Zb);
  k_scan<<<dim3(32), 512, 0, stream>>>(Zf, Zb, Wt1f, Wt1b, 768, 512, h0, c0, bufB,
                                       hnb + 2 * 8192, cnb + 2 * 8192);
  k_highway<<<dim3(256, 4), 256, 0, stream>>>(bufB, bufA, Wthw, bhw, bufA, (float*)nullptr);

  // layer 2: ys -> bufB; highway(Ys=bufB, Cur=bufA) -> out (fp32, final)
  k_pregemm<<<dim3(256, 6, 2), 256, 0, stream>>>(bufA, 512, Wt2f, Wt2b, 768, bf2, bb2, Zf, Zb);
  k_scan<<<dim3(32), 512, 0, stream>>>(Zf, Zb, Wt2f, Wt2b, 768, 512, h0, c0, bufB,
                                       hnb + 4 * 8192, cnb + 4 * 8192);
  k_highway<<<dim3(256, 4), 256, 0, stream>>>(bufB, bufA, Wthw, bhw, (u16*)nullptr, out);
}